// Round 6
// baseline (639.219 us; speedup 1.0000x reference)
//
#include <hip/hip_runtime.h>

// Gram-trick + MFMA. Ladder: 2310 -> 1380 (score2) -> 626 (MFMA gram/y_gemm).
// R6: gram BK=128 + XCD-combo swizzle + symmetry (21 tiles + mirror); sur_all 2px/thread.

#define HW 16384
typedef unsigned short u16;
typedef unsigned int u32;
typedef __attribute__((ext_vector_type(8))) short short8;
typedef __attribute__((ext_vector_type(4))) float f32x4;

// staging offsets (u16 elements)
#define S_CEN 0
#define S_QW 1048576
#define S_KW 1056768
#define S_VW 1581056
#define S_W1 2105344
#define S_B1 2142208
#define S_W2 2142336
#define S_B2 2143360
#define S_SW 2143392
#define S_OW 2143400
#define S_GAMMA 2208936
#define S_BETA 2209192
#define S_TOTAL 2209456

// compact Gram layout per batch (f32 elements)
#define G_D1 0       // 128x128, stride 128
#define G_D2 16384   // 128x1024, stride 1024
#define G_S 147456   // 4 blocks of 256x256, stride 256
#define G_SZ 409600

__device__ __forceinline__ float b2f(u16 u) { return __uint_as_float(((u32)u) << 16); }
__device__ __forceinline__ u16 f2b(float f) {
  u32 u = __float_as_uint(f);
  return (u16)((u + 0x7FFFu + ((u >> 16) & 1u)) >> 16);  // RNE
}
__device__ __forceinline__ float wave_sum(float v) {
  #pragma unroll
  for (int off = 32; off > 0; off >>= 1) v += __shfl_xor(v, off, 64);
  return v;
}
__device__ __forceinline__ float wave_max(float v) {
  #pragma unroll
  for (int off = 32; off > 0; off >>= 1) v = fmaxf(v, __shfl_xor(v, off, 64));
  return v;
}
__device__ __forceinline__ void unpack8(uint4 v, float* f) {
  f[0] = __uint_as_float(v.x << 16); f[1] = __uint_as_float(v.x & 0xFFFF0000u);
  f[2] = __uint_as_float(v.y << 16); f[3] = __uint_as_float(v.y & 0xFFFF0000u);
  f[4] = __uint_as_float(v.z << 16); f[5] = __uint_as_float(v.z & 0xFFFF0000u);
  f[6] = __uint_as_float(v.w << 16); f[7] = __uint_as_float(v.w & 0xFFFF0000u);
}

// ------------------------------------------------------------ dtype probe
__global__ void probe(const u32* __restrict__ g, int* __restrict__ flag) {
  if (threadIdx.x == 0) {
    int ok = 1;
    #pragma unroll
    for (int i = 0; i < 4; i++) {
      u32 w = g[i];
      u32 lo = w & 0xFFFFu, hi = w >> 16;
      ok &= (lo >= 0x3E00u && lo <= 0x4100u) ? 1 : 0;
      ok &= (hi >= 0x3E00u && hi <= 0x4100u) ? 1 : 0;
    }
    *flag = ok ? 0 : 1;  // 0 = bf16 inputs, 1 = f32 inputs
  }
}

// ------------------------------------------------------------ stage inputs -> bf16
__global__ __launch_bounds__(256) void convert_all(
    const void* p0, const void* p1, const void* p2, const void* p3,
    const void* p4, const void* p5, const void* p6, const void* p7,
    const void* p8, const void* p9, const void* p10, const void* p11,
    u16* __restrict__ S, const int* __restrict__ flag) {
  const void* src; int n; int off;
  switch (blockIdx.z) {
    case 0:  src = p0;  n = 1048576; off = S_CEN; break;
    case 1:  src = p1;  n = 8192;    off = S_QW; break;
    case 2:  src = p2;  n = 524288;  off = S_KW; break;
    case 3:  src = p3;  n = 524288;  off = S_VW; break;
    case 4:  src = p4;  n = 36864;   off = S_W1; break;
    case 5:  src = p5;  n = 128;     off = S_B1; break;
    case 6:  src = p6;  n = 1024;    off = S_W2; break;
    case 7:  src = p7;  n = 32;      off = S_B2; break;
    case 8:  src = p8;  n = 8;       off = S_SW; break;
    case 9:  src = p9;  n = 65536;   off = S_OW; break;
    case 10: src = p10; n = 256;     off = S_GAMMA; break;
    default: src = p11; n = 256;     off = S_BETA; break;
  }
  int idx = (blockIdx.x * 256 + threadIdx.x) * 4;
  if (idx >= n) return;
  u16* dst = S + off + idx;
  if (*flag) {
    float4 v = ((const float4*)src)[idx >> 2];
    dst[0] = f2b(v.x); dst[1] = f2b(v.y); dst[2] = f2b(v.z); dst[3] = f2b(v.w);
  } else {
    *(ushort4*)dst = ((const ushort4*)src)[idx >> 2];
  }
}

// ------------------------------------------- sur + cenx -> Mbuf (2 pixels/thread)
__global__ __launch_bounds__(256) void sur_all(
    const u16* __restrict__ cen, const u16* __restrict__ w1g,
    const u16* __restrict__ b1g, const u16* __restrict__ w2g,
    const u16* __restrict__ b2g, const u16* __restrict__ swg,
    u16* __restrict__ Mbuf) {
  const int si = blockIdx.z;
  const int d = 1 << si;  // 1,2,4,8
  __shared__ float w1s[9216];  // [tap][ci][co]
  __shared__ float w2s[256];
  __shared__ float b1s[32];
  __shared__ float b2s[8];
  const int t = threadIdx.x;
  for (int e = t; e < 9216; e += 256) {
    int tap = e >> 10, rem = e & 1023, ci = rem >> 5, co = rem & 31;
    w1s[e] = b2f(w1g[si * 9216 + co * 288 + ci * 9 + tap]);
  }
  w2s[t] = b2f(w2g[si * 256 + t]);
  if (t < 32) b1s[t] = b2f(b1g[si * 32 + t]);
  if (t < 8) b2s[t] = b2f(b2g[si * 8 + t]);
  __syncthreads();

  const int b = blockIdx.y;
  const int s = (blockIdx.x * 256 + t) * 2;   // even
  const int h = s >> 7, w = s & 127;          // w even, w+1 <= 127

  float s0 = b2f(swg[si * 2 + 0]), s1 = b2f(swg[si * 2 + 1]);
  float mx = fmaxf(s0, s1);
  float e0 = expf(s0 - mx), e1 = expf(s1 - mx);
  float w20 = e0 / (e0 + e1), w21 = e1 / (e0 + e1);

  const u16* cb = cen + (size_t)b * 32 * HW;

  float h1a[32], h1b[32];
  #pragma unroll
  for (int i = 0; i < 32; i++) { h1a[i] = 0.f; h1b[i] = 0.f; }
  for (int tap = 0; tap < 9; tap++) {
    int ky = tap / 3, kx = tap - ky * 3;
    int y = h + (ky - 1) * d;
    if (y < 0 || y >= 128) continue;
    int x0 = w + (kx - 1) * d, x1 = x0 + 1;
    bool ok0 = (x0 >= 0 && x0 < 128), ok1 = (x1 >= 0 && x1 < 128);
    if (!ok0 && !ok1) continue;
    int off = y * 128;
    const float* wt = &w1s[tap * 1024];
    for (int ci = 0; ci < 32; ci++) {
      float va = ok0 ? b2f(cb[(size_t)ci * HW + off + x0]) : 0.f;
      float vb = ok1 ? b2f(cb[(size_t)ci * HW + off + x1]) : 0.f;
      #pragma unroll
      for (int co = 0; co < 32; co++) {
        float ww = wt[ci * 32 + co];
        h1a[co] = fmaf(va, ww, h1a[co]);
        h1b[co] = fmaf(vb, ww, h1b[co]);
      }
    }
  }
  #pragma unroll
  for (int i = 0; i < 32; i++) {
    h1a[i] = fmaxf(h1a[i] + b1s[i], 0.f);
    h1b[i] = fmaxf(h1b[i] + b1s[i], 0.f);
  }

  float lga[8], lgb[8];
  #pragma unroll
  for (int k = 0; k < 8; k++) { lga[k] = b2s[k]; lgb[k] = b2s[k]; }
  for (int ci = 0; ci < 32; ci++) {
    float va = h1a[ci], vb = h1b[ci];
    #pragma unroll
    for (int k = 0; k < 8; k++) {
      float ww = w2s[k * 32 + ci];
      lga[k] = fmaf(va, ww, lga[k]);
      lgb[k] = fmaf(vb, ww, lgb[k]);
    }
  }
  {
    float lm = lga[0];
    #pragma unroll
    for (int k = 1; k < 8; k++) lm = fmaxf(lm, lga[k]);
    float ls = 0.f;
    #pragma unroll
    for (int k = 0; k < 8; k++) { lga[k] = expf(lga[k] - lm); ls += lga[k]; }
    float inv = w20 / ls;
    #pragma unroll
    for (int k = 0; k < 8; k++) lga[k] *= inv;
  }
  {
    float lm = lgb[0];
    #pragma unroll
    for (int k = 1; k < 8; k++) lm = fmaxf(lm, lgb[k]);
    float ls = 0.f;
    #pragma unroll
    for (int k = 0; k < 8; k++) { lgb[k] = expf(lgb[k] - lm); ls += lgb[k]; }
    float inv = w20 / ls;
    #pragma unroll
    for (int k = 0; k < 8; k++) lgb[k] *= inv;
  }

  const int dy[8] = {-d, -d, -d, 0, 0, d, d, d};
  const int dx[8] = {-d, 0, d, -d, d, -d, 0, d};
  int offa[8], offb[8];
  #pragma unroll
  for (int k = 0; k < 8; k++) {
    int y = h + dy[k]; y = y < 0 ? -y : (y > 127 ? 254 - y : y);
    int xa = w + dx[k]; xa = xa < 0 ? -xa : (xa > 127 ? 254 - xa : xa);
    int xb = w + 1 + dx[k]; xb = xb < 0 ? -xb : (xb > 127 ? 254 - xb : xb);
    offa[k] = y * 128 + xa;
    offb[k] = y * 128 + xb;
  }
  u16* Mb = Mbuf + (size_t)b * 1152 * HW;
  for (int c = 0; c < 32; c++) {
    const u16* cc = cb + (size_t)c * HW;
    float cva = b2f(cc[s]), cvb = b2f(cc[s + 1]);
    float nba[8], nbb[8];
    #pragma unroll
    for (int k = 0; k < 8; k++) { nba[k] = b2f(cc[offa[k]]); nbb[k] = b2f(cc[offb[k]]); }
    float sxa = 0.f, mna = 0.f, sxb = 0.f, mnb = 0.f;
    #pragma unroll
    for (int k = 0; k < 8; k++) {
      sxa = fmaf(lga[k], nba[k], sxa); mna += nba[k];
      sxb = fmaf(lgb[k], nbb[k], sxb); mnb += nbb[k];
    }
    float suma = sxa + cva * w21, sumb = sxb + cvb * w21;
    u32 cx = (u32)f2b(mna * 0.125f * w20 + cva * w21) |
             ((u32)f2b(mnb * 0.125f * w20 + cvb * w21) << 16);
    *(u32*)&Mb[(size_t)(32 * si + c) * HW + s] = cx;
    #pragma unroll
    for (int k = 0; k < 8; k++) {
      u32 pk = (u32)f2b(nba[k] - suma) | ((u32)f2b(nbb[k] - sumb) << 16);
      *(u32*)&Mb[(size_t)(128 + 256 * si + k * 32 + c) * HW + s] = pk;
    }
  }
}

// -------------------- Gram via MFMA: BK=128, 21 tiles, XCD-combo swizzle, atomics
// grid: 672 blocks, id = tile*32 + combo; combo = ks*2+b -> id%8 = combo%8 (same
// s-range groups on one XCD for L2 reuse).
__global__ __launch_bounds__(256) void gram_mfma(
    const u16* __restrict__ Mbuf, float* __restrict__ G) {
  const int id = blockIdx.x;
  const int tile = id >> 5, combo = id & 31;
  const int ks = combo >> 1, b = combo & 1;
  int r0, c0, gstride; size_t goff;
  if (tile == 0) { r0 = 0; c0 = 0; goff = G_D1; gstride = 128; }
  else if (tile < 9) { r0 = 0; c0 = 128 * tile; goff = G_D2 + (size_t)(tile - 1) * 128; gstride = 1024; }
  else if (tile < 17) {
    int t2 = tile - 9; int j = t2 >> 1, p = t2 & 1;
    r0 = 128 + 256 * j + 128 * p; c0 = r0;
    goff = G_S + (size_t)j * 65536 + (size_t)p * (128 * 256 + 128); gstride = 256;
  } else {  // S_j offdiag upper (p=0,q=1); lower filled by mirror_S
    int j = tile - 17;
    r0 = 128 + 256 * j; c0 = r0 + 128;
    goff = G_S + (size_t)j * 65536 + 128; gstride = 256;
  }
  const u16* Mb = Mbuf + (size_t)b * 1152 * HW;
  __shared__ u16 As[128][132];  // pad 132 (66 u32, odd*2): 4-way max on frag reads
  __shared__ u16 Bs[128][132];
  const int t = threadIdx.x;
  const int lane = t & 63, w = t >> 6;
  const int wr = w >> 1, wc = w & 1;
  const int m = lane & 15, quad = lane >> 4;
  f32x4 acc[4][4];
  #pragma unroll
  for (int i = 0; i < 4; i++)
    #pragma unroll
    for (int j = 0; j < 4; j++) acc[i][j] = (f32x4){0.f, 0.f, 0.f, 0.f};

  for (int s0 = ks * 1024; s0 < ks * 1024 + 1024; s0 += 128) {
    for (int e = t; e < 2048; e += 256) {
      int r = e >> 4, c8 = (e & 15) * 8;
      *(uint4*)&As[r][c8] = *(const uint4*)&Mb[(size_t)(r0 + r) * HW + s0 + c8];
      *(uint4*)&Bs[r][c8] = *(const uint4*)&Mb[(size_t)(c0 + r) * HW + s0 + c8];
    }
    __syncthreads();
    #pragma unroll
    for (int k0 = 0; k0 < 128; k0 += 32) {
      short8 af[4], bf[4];
      #pragma unroll
      for (int i = 0; i < 4; i++) af[i] = *(const short8*)&As[wr * 64 + i * 16 + m][k0 + quad * 8];
      #pragma unroll
      for (int j = 0; j < 4; j++) bf[j] = *(const short8*)&Bs[wc * 64 + j * 16 + m][k0 + quad * 8];
      #pragma unroll
      for (int i = 0; i < 4; i++)
        #pragma unroll
        for (int j = 0; j < 4; j++)
          acc[i][j] = __builtin_amdgcn_mfma_f32_16x16x32_bf16(af[i], bf[j], acc[i][j], 0, 0, 0);
    }
    __syncthreads();
  }
  float* Gb = G + (size_t)b * G_SZ + goff;
  #pragma unroll
  for (int i = 0; i < 4; i++)
    #pragma unroll
    for (int j = 0; j < 4; j++) {
      int col = wc * 64 + j * 16 + m;
      #pragma unroll
      for (int r = 0; r < 4; r++) {
        int row = wr * 64 + i * 16 + quad * 4 + r;
        atomicAdd(&Gb[(size_t)row * gstride + col], acc[i][j][r]);
      }
    }
}

// ------------------------------------- mirror S_j lower-left = upper-right^T
__global__ __launch_bounds__(256) void mirror_S(float* __restrict__ G) {
  const int j = blockIdx.x & 3, b = blockIdx.x >> 2;
  float* base = G + (size_t)b * G_SZ + G_S + (size_t)j * 65536;
  const int t = threadIdx.x;
  for (int e = t; e < 16384; e += 256) {
    int rr = e >> 7, cc = e & 127;
    base[(size_t)(128 + rr) * 256 + cc] = base[(size_t)cc * 256 + 128 + rr];
  }
}

// ------------------------------------------------------------------ Q row inv-norms
__global__ __launch_bounds__(64) void qnorm(
    const u16* __restrict__ qw, const float* __restrict__ G,
    float* __restrict__ invQ) {
  const int bn = blockIdx.x, b = bn >> 2, n = bn & 3;
  const int rq = threadIdx.x;
  const int i = rq & 3, q1r = rq >> 2;
  const u16* qr = qw + ((size_t)(i * 64) + 16 * n + q1r) * 32;
  float v[32];
  #pragma unroll
  for (int c = 0; c < 32; c++) v[c] = b2f(qr[c]);
  const float* D1 = G + (size_t)b * G_SZ;
  float ss = 0.f;
  for (int c = 0; c < 32; c++) {
    float tmp = 0.f;
    #pragma unroll
    for (int c2 = 0; c2 < 32; c2++) tmp = fmaf(v[c2], D1[(size_t)(32 * i + c2) * 128 + 32 * i + c], tmp);
    ss = fmaf(tmp, v[c], ss);
  }
  invQ[bn * 64 + rq] = 1.f / fmaxf(sqrtf(fmaxf(ss, 0.f)), 1e-12f);
}

// ------------------------------------------------------------------ K row inv-norms
__global__ __launch_bounds__(256) void knorm(
    const u16* __restrict__ kw, const float* __restrict__ G,
    float* __restrict__ invK) {
  const int rk = blockIdx.x, n = blockIdx.y, b = blockIdx.z;
  const int j = rk & 3, kk = rk >> 2;
  const u16* kr = kw + ((size_t)(j * 512) + 128 * n + kk) * 256;
  __shared__ float vs[256];
  const int t = threadIdx.x;
  vs[t] = b2f(kr[t]);
  __syncthreads();
  const float* S = G + (size_t)b * G_SZ + G_S + (size_t)j * 65536;
  float tmp = 0.f;
  for (int c2 = 0; c2 < 256; c2++) tmp = fmaf(vs[c2], S[(size_t)c2 * 256 + t], tmp);
  tmp *= vs[t];
  tmp = wave_sum(tmp);
  __shared__ float red[4];
  if ((t & 63) == 0) red[t >> 6] = tmp;
  __syncthreads();
  if (t == 0) {
    float tot = fmaxf(red[0] + red[1] + red[2] + red[3], 0.f);
    invK[(size_t)(b * 4 + n) * 512 + rk] = 1.f / fmaxf(sqrtf(tot), 1e-12f);
  }
}

// ------------------- score2: per (j,n,b): KD = D2_j . kw^T, then blockdiag(q_w).KD
__global__ __launch_bounds__(256) void score2(
    const u16* __restrict__ qw, const u16* __restrict__ kw,
    const float* __restrict__ G, float* __restrict__ score) {
  const int j = blockIdx.x, n = blockIdx.y, b = blockIdx.z;
  const float* D2 = G + (size_t)b * G_SZ + G_D2;
  const u16* kwb = kw + ((size_t)(j * 512) + 128 * n) * 256;
  __shared__ float As[64][132];
  __shared__ u16 Bs[64][128];
  __shared__ float KD[128][132];
  __shared__ float qws[64][32];
  const int t = threadIdx.x, tx = t & 15, ty = t >> 4;
  float acc[8][8];
  #pragma unroll
  for (int i = 0; i < 8; i++)
    #pragma unroll
    for (int jj = 0; jj < 8; jj++) acc[i][jj] = 0.f;
  for (int ch0 = 0; ch0 < 256; ch0 += 64) {
    for (int e = t; e < 8192; e += 256) {
      int r = e >> 6, kc = e & 63;
      As[kc][r] = D2[(size_t)r * 1024 + j * 256 + ch0 + kc];
      Bs[kc][r] = kwb[(size_t)r * 256 + ch0 + kc];
    }
    __syncthreads();
    #pragma unroll 4
    for (int kc = 0; kc < 64; kc++) {
      float4 a0 = *(const float4*)&As[kc][ty * 8];
      float4 a1 = *(const float4*)&As[kc][ty * 8 + 4];
      uint4 bv = *(const uint4*)&Bs[kc][tx * 8];
      float a[8] = {a0.x, a0.y, a0.z, a0.w, a1.x, a1.y, a1.z, a1.w};
      float bb[8];
      unpack8(bv, bb);
      #pragma unroll
      for (int i = 0; i < 8; i++)
        #pragma unroll
        for (int jj = 0; jj < 8; jj++) acc[i][jj] = fmaf(a[i], bb[jj], acc[i][jj]);
    }
    __syncthreads();
  }
  #pragma unroll
  for (int i = 0; i < 8; i++)
    #pragma unroll
    for (int jj = 0; jj < 8; jj++) KD[ty * 8 + i][tx * 8 + jj] = acc[i][jj];
  for (int e = t; e < 2048; e += 256) {
    int q = e >> 5, c = e & 31;
    int i = q & 3, q1r = q >> 2;
    qws[q][c] = b2f(qw[((size_t)(i * 64) + 16 * n + q1r) * 32 + c]);
  }
  __syncthreads();
  float* sb = score + (size_t)(b * 4 + n) * 64 * 512;
  for (int e = t; e < 8192; e += 256) {
    int q = e >> 7, kk = e & 127;
    int i = q & 3;
    float s = 0.f;
    #pragma unroll
    for (int c = 0; c < 32; c++) s = fmaf(qws[q][c], KD[i * 32 + c][kk], s);
    sb[(size_t)q * 512 + 4 * kk + j] = s;
  }
}

// ------------------------------------------ scale + InstanceNorm + row softmax
__global__ __launch_bounds__(256) void in_softmax(
    float* __restrict__ score, const float* __restrict__ invQ,
    const float* __restrict__ invK) {
  const int bn = blockIdx.x;
  float* sb = score + (size_t)bn * 64 * 512;
  const float* iQ = invQ + bn * 64;
  const float* iK = invK + bn * 512;
  const int t = threadIdx.x;
  float sum = 0.f, ss = 0.f;
  const float isc = 1.f / 128.f;
  for (int e = t; e < 32768; e += 256) {
    int q = e >> 9, kk = e & 511;
    float v = sb[e] * iQ[q] * iK[kk] * isc;
    sb[e] = v;
    sum += v; ss += v * v;
  }
  __shared__ float red[8];
  sum = wave_sum(sum); ss = wave_sum(ss);
  if ((t & 63) == 0) { red[t >> 6] = sum; red[4 + (t >> 6)] = ss; }
  __syncthreads();
  float mean = (red[0] + red[1] + red[2] + red[3]) * (1.f / 32768.f);
  float var = (red[4] + red[5] + red[6] + red[7]) * (1.f / 32768.f) - mean * mean;
  float istd = rsqrtf(var + 1e-5f);
  const int wv = t >> 6, lane = t & 63;
  for (int r = wv; r < 64; r += 4) {
    float z[8];
    float m = -1e30f;
    #pragma unroll
    for (int j = 0; j < 8; j++) {
      z[j] = (sb[(size_t)r * 512 + lane + 64 * j] - mean) * istd;
      m = fmaxf(m, z[j]);
    }
    m = wave_max(m);
    float sloc = 0.f;
    #pragma unroll
    for (int j = 0; j < 8; j++) { z[j] = expf(z[j] - m); sloc += z[j]; }
    sloc = wave_sum(sloc);
    float rinv = 1.f / sloc;
    #pragma unroll
    for (int j = 0; j < 8; j++) sb[(size_t)r * 512 + lane + 64 * j] = z[j] * rinv;
  }
}

// ------------------------------------------- W2[bn][q][j*256+ch] = attn . v_w
__global__ __launch_bounds__(256) void attnW2(
    const float* __restrict__ attn, const u16* __restrict__ vw,
    float* __restrict__ W2) {
  const int n = blockIdx.x, q0 = blockIdx.y * 8, b = blockIdx.z, bn = b * 4 + n;
  const float* ab = attn + (size_t)bn * 64 * 512;
  const int t = threadIdx.x;
  const int j = t >> 6, lane = t & 63;
  __shared__ float at_s[8][512];
  for (int e = t; e < 4096; e += 256) {
    int qg = e >> 9, kcol = e & 511;
    at_s[qg][kcol] = ab[(size_t)(q0 + qg) * 512 + kcol];
  }
  __syncthreads();
  float acc[8][4];
  #pragma unroll
  for (int qg = 0; qg < 8; qg++)
    #pragma unroll
    for (int cc = 0; cc < 4; cc++) acc[qg][cc] = 0.f;
  for (int kk = 0; kk < 128; kk++) {
    const u16* vrow = vw + ((size_t)(j * 512) + 128 * n + kk) * 256 + lane;
    float v0 = b2f(vrow[0]), v1 = b2f(vrow[64]), v2 = b2f(vrow[128]), v3 = b2f(vrow[192]);
    #pragma unroll
    for (int qg = 0; qg < 8; qg++) {
      float a = at_s[qg][4 * kk + j];
      acc[qg][0] = fmaf(a, v0, acc[qg][0]);
      acc[qg][1] = fmaf(a, v1, acc[qg][1]);
      acc[qg][2] = fmaf(a, v2, acc[qg][2]);
      acc[qg][3] = fmaf(a, v3, acc[qg][3]);
    }
  }
  #pragma unroll
  for (int qg = 0; qg < 8; qg++)
    #pragma unroll
    for (int cc = 0; cc < 4; cc++)
      W2[((size_t)bn * 64 + q0 + qg) * 1024 + j * 256 + lane + 64 * cc] = acc[qg][cc];
}

// ------------------------------------------ Wfin16[b][o][jc] = bf16(out_w . W2)
__global__ __launch_bounds__(256) void wfin_k(
    const u16* __restrict__ ow, const float* __restrict__ W2,
    u16* __restrict__ Wfin16) {
  const int jc = blockIdx.x, b = blockIdx.y;
  __shared__ float col[256];
  const int t = threadIdx.x;
  col[t] = W2[((size_t)b * 256 + t) * 1024 + jc];
  __syncthreads();
  float acc = 0.f;
  const u16* owr = ow + (size_t)t * 256;
  for (int c = 0; c < 256; c++) acc = fmaf(b2f(owr[c]), col[c], acc);
  Wfin16[((size_t)b * 256 + t) * 1024 + jc] = f2b(acc);
}

// -------------------------------------- y = Wfin(bf16) @ sur via MFMA (bf16 out)
__global__ __launch_bounds__(256) void y_gemm_mfma(
    const u16* __restrict__ Wfin16, const u16* __restrict__ Mbuf,
    u16* __restrict__ ybuf) {
  const int b = blockIdx.z, row0 = blockIdx.y * 128, col0 = blockIdx.x * 128;
  __shared__ u16 As[128][72];  // [o-row][k]
  __shared__ u16 Bs[128][72];  // [s-col][k] transposed staging
  const u16* Ab = Wfin16 + (size_t)b * 256 * 1024;
  const u16* Mb = Mbuf + (size_t)b * 1152 * HW + (size_t)128 * HW;
  const int t = threadIdx.x;
  const int lane = t & 63, w = t >> 6;
  const int wr = w >> 1, wc = w & 1;
  const int m = lane & 15, quad = lane >> 4;
  f32x4 acc[4][4];
  #pragma unroll
  for (int i = 0; i < 4; i++)
    #pragma unroll
    for (int j = 0; j < 4; j++) acc[i][j] = (f32x4){0.f, 0.f, 0.f, 0.f};

  for (int k0c = 0; k0c < 1024; k0c += 64) {
    for (int e = t; e < 1024; e += 256) {
      int r = e >> 3, kc8 = (e & 7) * 8;
      *(uint4*)&As[r][kc8] = *(const uint4*)&Ab[(size_t)(row0 + r) * 1024 + k0c + kc8];
    }
    for (int e = t; e < 1024; e += 256) {
      int kc = e >> 4, c8 = (e & 15) * 8;
      uint4 v = *(const uint4*)&Mb[(size_t)(k0c + kc) * HW + col0 + c8];
      u16 tmp[8]; *(uint4*)tmp = v;
      #pragma unroll
      for (int uu = 0; uu < 8; uu++) {
        int u = (uu + lane) & 7;
        Bs[c8 + u][kc] = tmp[u];
      }
    }
    __syncthreads();
    #pragma unroll
    for (int k0 = 0; k0 < 64; k0 += 32) {
      short8 af[4], bf[4];
      #pragma unroll
      for (int i = 0; i < 4; i++) af[i] = *(const short8*)&As[wr * 64 + i * 16 + m][k0 + quad * 8];
      #pragma unroll
      for (int j = 0; j < 4; j++) bf[j] = *(const short8*)&Bs[wc * 64 + j * 16 + m][k0 + quad * 8];
      #pragma unroll
      for (int i = 0; i < 4; i++)
        #pragma unroll
        for (int j = 0; j < 4; j++)
          acc[i][j] = __builtin_amdgcn_mfma_f32_16x16x32_bf16(af[i], bf[j], acc[i][j], 0, 0, 0);
    }
    __syncthreads();
  }
  #pragma unroll
  for (int i = 0; i < 4; i++)
    #pragma unroll
    for (int j = 0; j < 4; j++) {
      int col = col0 + wc * 64 + j * 16 + m;
      #pragma unroll
      for (int r = 0; r < 4; r++) {
        int row = row0 + wr * 64 + i * 16 + quad * 4 + r;
        ybuf[((size_t)b * 256 + row) * HW + col] = f2b(acc[i][j][r]);
      }
    }
}

// ---------------------------------------------------------------- BatchNorm
__global__ __launch_bounds__(256) void bn_stats(
    const u16* __restrict__ y, float* __restrict__ st) {
  const int o = blockIdx.x;
  const int t = threadIdx.x;
  float sum = 0.f, ss = 0.f;
  for (int bb = 0; bb < 2; bb++) {
    const u16* p = y + ((size_t)bb * 256 + o) * HW;
    for (int e = t; e < HW / 8; e += 256) {
      uint4 v = ((const uint4*)p)[e];
      float f[8];
      unpack8(v, f);
      #pragma unroll
      for (int k = 0; k < 8; k++) { sum += f[k]; ss += f[k] * f[k]; }
    }
  }
  __shared__ float red[8];
  sum = wave_sum(sum); ss = wave_sum(ss);
  if ((t & 63) == 0) { red[t >> 6] = sum; red[4 + (t >> 6)] = ss; }
  __syncthreads();
  if (t == 0) {
    float mean = (red[0] + red[1] + red[2] + red[3]) / 32768.f;
    float var = (red[4] + red[5] + red[6] + red[7]) / 32768.f - mean * mean;
    st[o * 2] = mean;
    st[o * 2 + 1] = rsqrtf(var + 1e-5f);
  }
}

__global__ __launch_bounds__(256) void bn_apply(
    const u16* __restrict__ y, const float* __restrict__ st,
    const u16* __restrict__ gamma, const u16* __restrict__ beta,
    const int* __restrict__ flag, void* __restrict__ out) {
  const int idx8 = blockIdx.x * 256 + threadIdx.x;
  const int r = idx8 >> 11;
  const int o = r & 255;
  float mean = st[o * 2], istd = st[o * 2 + 1];
  float g = b2f(gamma[o]), be = b2f(beta[o]);
  uint4 v = ((const uint4*)y)[idx8];
  float f[8];
  unpack8(v, f);
  float rr[8];
  #pragma unroll
  for (int k = 0; k < 8; k++) rr[k] = fmaxf((f[k] - mean) * istd * g + be, 0.f);
  if (*flag) {
    float* of = (float*)out + (size_t)idx8 * 8;
    *(float4*)of = make_float4(rr[0], rr[1], rr[2], rr[3]);
    *(float4*)(of + 4) = make_float4(rr[4], rr[5], rr[6], rr[7]);
  } else {
    u32 p0 = (u32)f2b(rr[0]) | ((u32)f2b(rr[1]) << 16);
    u32 p1 = (u32)f2b(rr[2]) | ((u32)f2b(rr[3]) << 16);
    u32 p2 = (u32)f2b(rr[4]) | ((u32)f2b(rr[5]) << 16);
    u32 p3 = (u32)f2b(rr[6]) | ((u32)f2b(rr[7]) << 16);
    ((uint4*)out)[idx8] = make_uint4(p0, p1, p2, p3);
  }
}

// ----------------------------------------------------------------------------
extern "C" void kernel_launch(void* const* d_in, const int* in_sizes, int n_in,
                              void* d_out, int out_size, void* d_ws, size_t ws_size,
                              hipStream_t stream) {
  float* G     = (float*)d_ws;           // 819,200 f32 (2 x G_SZ)
  float* score = G + 819200;             // 262,144
  float* invQ  = score + 262144;         // 512
  float* invK  = invQ + 512;             // 4,096
  float* W2    = invK + 4096;            // 524,288
  float* Wfin  = W2 + 524288;            // slot reused: u16 Wfin16
  float* bnst  = Wfin + 524288;          // 512
  int* flag    = (int*)(bnst + 512);     // 16
  u16* Sbuf    = (u16*)(flag + 16);      // S_TOTAL u16
  u16* Mbuf    = Sbuf + S_TOTAL;         // 37,748,736 u16
  u16* ybuf    = Mbuf + 37748736;        // 8,388,608 u16
  u16* Wfin16  = (u16*)Wfin;

  probe<<<1, 64, 0, stream>>>((const u32*)d_in[10], flag);
  convert_all<<<dim3(1024, 1, 12), 256, 0, stream>>>(
      d_in[0], d_in[1], d_in[2], d_in[3], d_in[4], d_in[5], d_in[6], d_in[7],
      d_in[8], d_in[9], d_in[10], d_in[11], Sbuf, flag);

  sur_all<<<dim3(32, 2, 4), 256, 0, stream>>>(
      Sbuf + S_CEN, Sbuf + S_W1, Sbuf + S_B1, Sbuf + S_W2, Sbuf + S_B2,
      Sbuf + S_SW, Mbuf);
  hipMemsetAsync(G, 0, 819200 * sizeof(float), stream);
  gram_mfma<<<672, 256, 0, stream>>>(Mbuf, G);
  mirror_S<<<8, 256, 0, stream>>>(G);
  qnorm<<<8, 64, 0, stream>>>(Sbuf + S_QW, G, invQ);
  knorm<<<dim3(512, 4, 2), 256, 0, stream>>>(Sbuf + S_KW, G, invK);
  score2<<<dim3(4, 4, 2), 256, 0, stream>>>(Sbuf + S_QW, Sbuf + S_KW, G, score);
  in_softmax<<<8, 256, 0, stream>>>(score, invQ, invK);
  attnW2<<<dim3(4, 8, 2), 256, 0, stream>>>(score, Sbuf + S_VW, W2);
  wfin_k<<<dim3(1024, 2), 256, 0, stream>>>(Sbuf + S_OW, W2, Wfin16);
  y_gemm_mfma<<<dim3(128, 2, 2), 256, 0, stream>>>(Wfin16, Mbuf, ybuf);
  bn_stats<<<256, 256, 0, stream>>>(ybuf, bnst);
  bn_apply<<<4096, 256, 0, stream>>>(ybuf, bnst, Sbuf + S_GAMMA, Sbuf + S_BETA,
                                     flag, d_out);
}

// Round 7
// 595.280 us; speedup vs baseline: 1.0738x; 1.0738x over previous
//
#include <hip/hip_runtime.h>

// Gram-trick + MFMA. Ladder: 2310 -> 1380 (score2) -> 626 (MFMA) -> 639 (R6 mixed:
// gram improved, sur_all 2px regressed to 151us latency-bound).
// R7: split sur_all -> sur_w (conv+softmax, 512 blk) + sur_scatter (1024 blk, stream).

#define HW 16384
typedef unsigned short u16;
typedef unsigned int u32;
typedef __attribute__((ext_vector_type(8))) short short8;
typedef __attribute__((ext_vector_type(4))) float f32x4;

// staging offsets (u16 elements)
#define S_CEN 0
#define S_QW 1048576
#define S_KW 1056768
#define S_VW 1581056
#define S_W1 2105344
#define S_B1 2142208
#define S_W2 2142336
#define S_B2 2143360
#define S_SW 2143392
#define S_OW 2143400
#define S_GAMMA 2208936
#define S_BETA 2209192
#define S_TOTAL 2209456

// compact Gram layout per batch (f32 elements)
#define G_D1 0       // 128x128, stride 128
#define G_D2 16384   // 128x1024, stride 1024
#define G_S 147456   // 4 blocks of 256x256, stride 256
#define G_SZ 409600

__device__ __forceinline__ float b2f(u16 u) { return __uint_as_float(((u32)u) << 16); }
__device__ __forceinline__ u16 f2b(float f) {
  u32 u = __float_as_uint(f);
  return (u16)((u + 0x7FFFu + ((u >> 16) & 1u)) >> 16);  // RNE
}
__device__ __forceinline__ float wave_sum(float v) {
  #pragma unroll
  for (int off = 32; off > 0; off >>= 1) v += __shfl_xor(v, off, 64);
  return v;
}
__device__ __forceinline__ float wave_max(float v) {
  #pragma unroll
  for (int off = 32; off > 0; off >>= 1) v = fmaxf(v, __shfl_xor(v, off, 64));
  return v;
}
__device__ __forceinline__ void unpack8(uint4 v, float* f) {
  f[0] = __uint_as_float(v.x << 16); f[1] = __uint_as_float(v.x & 0xFFFF0000u);
  f[2] = __uint_as_float(v.y << 16); f[3] = __uint_as_float(v.y & 0xFFFF0000u);
  f[4] = __uint_as_float(v.z << 16); f[5] = __uint_as_float(v.z & 0xFFFF0000u);
  f[6] = __uint_as_float(v.w << 16); f[7] = __uint_as_float(v.w & 0xFFFF0000u);
}

// ------------------------------------------------------------ dtype probe
__global__ void probe(const u32* __restrict__ g, int* __restrict__ flag) {
  if (threadIdx.x == 0) {
    int ok = 1;
    #pragma unroll
    for (int i = 0; i < 4; i++) {
      u32 w = g[i];
      u32 lo = w & 0xFFFFu, hi = w >> 16;
      ok &= (lo >= 0x3E00u && lo <= 0x4100u) ? 1 : 0;
      ok &= (hi >= 0x3E00u && hi <= 0x4100u) ? 1 : 0;
    }
    *flag = ok ? 0 : 1;  // 0 = bf16 inputs, 1 = f32 inputs
  }
}

// ------------------------------------------------------------ stage inputs -> bf16
__global__ __launch_bounds__(256) void convert_all(
    const void* p0, const void* p1, const void* p2, const void* p3,
    const void* p4, const void* p5, const void* p6, const void* p7,
    const void* p8, const void* p9, const void* p10, const void* p11,
    u16* __restrict__ S, const int* __restrict__ flag) {
  const void* src; int n; int off;
  switch (blockIdx.z) {
    case 0:  src = p0;  n = 1048576; off = S_CEN; break;
    case 1:  src = p1;  n = 8192;    off = S_QW; break;
    case 2:  src = p2;  n = 524288;  off = S_KW; break;
    case 3:  src = p3;  n = 524288;  off = S_VW; break;
    case 4:  src = p4;  n = 36864;   off = S_W1; break;
    case 5:  src = p5;  n = 128;     off = S_B1; break;
    case 6:  src = p6;  n = 1024;    off = S_W2; break;
    case 7:  src = p7;  n = 32;      off = S_B2; break;
    case 8:  src = p8;  n = 8;       off = S_SW; break;
    case 9:  src = p9;  n = 65536;   off = S_OW; break;
    case 10: src = p10; n = 256;     off = S_GAMMA; break;
    default: src = p11; n = 256;     off = S_BETA; break;
  }
  int idx = (blockIdx.x * 256 + threadIdx.x) * 4;
  if (idx >= n) return;
  u16* dst = S + off + idx;
  if (*flag) {
    float4 v = ((const float4*)src)[idx >> 2];
    dst[0] = f2b(v.x); dst[1] = f2b(v.y); dst[2] = f2b(v.z); dst[3] = f2b(v.w);
  } else {
    *(ushort4*)dst = ((const ushort4*)src)[idx >> 2];
  }
}

// ------------------- sur_w: conv + 8-way softmax weights -> lgbuf[b][si][s][8] f32
__global__ __launch_bounds__(256) void sur_w(
    const u16* __restrict__ cen, const u16* __restrict__ w1g,
    const u16* __restrict__ b1g, const u16* __restrict__ w2g,
    const u16* __restrict__ b2g, const u16* __restrict__ swg,
    float* __restrict__ lgbuf) {
  const int si = blockIdx.z;
  const int d = 1 << si;
  __shared__ float w1s[9216];  // [tap][ci][co]
  __shared__ float w2s[256];
  __shared__ float b1s[32];
  __shared__ float b2s[8];
  const int t = threadIdx.x;
  for (int e = t; e < 9216; e += 256) {
    int tap = e >> 10, rem = e & 1023, ci = rem >> 5, co = rem & 31;
    w1s[e] = b2f(w1g[si * 9216 + co * 288 + ci * 9 + tap]);
  }
  w2s[t] = b2f(w2g[si * 256 + t]);
  if (t < 32) b1s[t] = b2f(b1g[si * 32 + t]);
  if (t < 8) b2s[t] = b2f(b2g[si * 8 + t]);
  __syncthreads();

  const int b = blockIdx.y;
  const int s = blockIdx.x * 256 + t;
  const int h = s >> 7, w = s & 127;

  float s0 = b2f(swg[si * 2 + 0]), s1 = b2f(swg[si * 2 + 1]);
  float mx = fmaxf(s0, s1);
  float e0 = expf(s0 - mx), e1 = expf(s1 - mx);
  float w20 = e0 / (e0 + e1);

  const u16* cb = cen + (size_t)b * 32 * HW;

  float h1[32];
  #pragma unroll
  for (int i = 0; i < 32; i++) h1[i] = 0.f;
  for (int tap = 0; tap < 9; tap++) {
    int ky = tap / 3, kx = tap - ky * 3;
    int y = h + (ky - 1) * d, x = w + (kx - 1) * d;
    if (y < 0 || y >= 128 || x < 0 || x >= 128) continue;
    int off = y * 128 + x;
    const float* wt = &w1s[tap * 1024];
    for (int ci = 0; ci < 32; ci++) {
      float v = b2f(cb[(size_t)ci * HW + off]);
      #pragma unroll
      for (int co = 0; co < 32; co++) h1[co] = fmaf(v, wt[ci * 32 + co], h1[co]);
    }
  }
  #pragma unroll
  for (int i = 0; i < 32; i++) h1[i] = fmaxf(h1[i] + b1s[i], 0.f);

  float lg[8];
  #pragma unroll
  for (int k = 0; k < 8; k++) lg[k] = b2s[k];
  for (int ci = 0; ci < 32; ci++) {
    float v = h1[ci];
    #pragma unroll
    for (int k = 0; k < 8; k++) lg[k] = fmaf(v, w2s[k * 32 + ci], lg[k]);
  }
  float lm = lg[0];
  #pragma unroll
  for (int k = 1; k < 8; k++) lm = fmaxf(lm, lg[k]);
  float ls = 0.f;
  #pragma unroll
  for (int k = 0; k < 8; k++) { lg[k] = expf(lg[k] - lm); ls += lg[k]; }
  float inv = w20 / ls;
  float* lp = lgbuf + ((size_t)(b * 4 + si) * HW + s) * 8;
  *(float4*)lp = make_float4(lg[0] * inv, lg[1] * inv, lg[2] * inv, lg[3] * inv);
  *(float4*)(lp + 4) = make_float4(lg[4] * inv, lg[5] * inv, lg[6] * inv, lg[7] * inv);
}

// ------------- sur_scatter: neighbors + sumx/cenx/sur writes (2px, 8ch per thread)
__global__ __launch_bounds__(256) void sur_scatter(
    const u16* __restrict__ cen, const float* __restrict__ lgbuf,
    const u16* __restrict__ swg, u16* __restrict__ Mbuf) {
  const int z = blockIdx.z;
  const int b = z >> 2, si = z & 3, d = 1 << si;
  const int c0 = blockIdx.y * 8;
  const int t = threadIdx.x;
  const int s = (blockIdx.x * 256 + t) * 2;  // even
  const int h = s >> 7, w = s & 127;

  float s0 = b2f(swg[si * 2 + 0]), s1 = b2f(swg[si * 2 + 1]);
  float mx = fmaxf(s0, s1);
  float e0 = expf(s0 - mx), e1 = expf(s1 - mx);
  float w20 = e0 / (e0 + e1), w21 = e1 / (e0 + e1);

  const float* lpa = lgbuf + ((size_t)(b * 4 + si) * HW + s) * 8;
  float4 la0 = *(const float4*)lpa, la1 = *(const float4*)(lpa + 4);
  float4 lb0 = *(const float4*)(lpa + 8), lb1 = *(const float4*)(lpa + 12);
  float lga[8] = {la0.x, la0.y, la0.z, la0.w, la1.x, la1.y, la1.z, la1.w};
  float lgb[8] = {lb0.x, lb0.y, lb0.z, lb0.w, lb1.x, lb1.y, lb1.z, lb1.w};

  const int dy[8] = {-d, -d, -d, 0, 0, d, d, d};
  const int dx[8] = {-d, 0, d, -d, d, -d, 0, d};
  int offa[8], offb[8];
  #pragma unroll
  for (int k = 0; k < 8; k++) {
    int y = h + dy[k]; y = y < 0 ? -y : (y > 127 ? 254 - y : y);
    int xa = w + dx[k]; xa = xa < 0 ? -xa : (xa > 127 ? 254 - xa : xa);
    int xb = w + 1 + dx[k]; xb = xb < 0 ? -xb : (xb > 127 ? 254 - xb : xb);
    offa[k] = y * 128 + xa;
    offb[k] = y * 128 + xb;
  }
  const u16* cb = cen + (size_t)b * 32 * HW;
  u16* Mb = Mbuf + (size_t)b * 1152 * HW;
  for (int c = c0; c < c0 + 8; c++) {
    const u16* cc = cb + (size_t)c * HW;
    u32 cvp = *(const u32*)&cc[s];
    float cva = __uint_as_float(cvp << 16), cvb = __uint_as_float(cvp & 0xFFFF0000u);
    float nba[8], nbb[8];
    #pragma unroll
    for (int k = 0; k < 8; k++) { nba[k] = b2f(cc[offa[k]]); nbb[k] = b2f(cc[offb[k]]); }
    float sxa = 0.f, mna = 0.f, sxb = 0.f, mnb = 0.f;
    #pragma unroll
    for (int k = 0; k < 8; k++) {
      sxa = fmaf(lga[k], nba[k], sxa); mna += nba[k];
      sxb = fmaf(lgb[k], nbb[k], sxb); mnb += nbb[k];
    }
    float suma = sxa + cva * w21, sumb = sxb + cvb * w21;
    u32 cx = (u32)f2b(mna * 0.125f * w20 + cva * w21) |
             ((u32)f2b(mnb * 0.125f * w20 + cvb * w21) << 16);
    *(u32*)&Mb[(size_t)(32 * si + c) * HW + s] = cx;
    #pragma unroll
    for (int k = 0; k < 8; k++) {
      u32 pk = (u32)f2b(nba[k] - suma) | ((u32)f2b(nbb[k] - sumb) << 16);
      *(u32*)&Mb[(size_t)(128 + 256 * si + k * 32 + c) * HW + s] = pk;
    }
  }
}

// -------------------- Gram via MFMA: BK=128, 21 tiles, XCD-combo swizzle, atomics
__global__ __launch_bounds__(256) void gram_mfma(
    const u16* __restrict__ Mbuf, float* __restrict__ G) {
  const int id = blockIdx.x;
  const int tile = id >> 5, combo = id & 31;
  const int ks = combo >> 1, b = combo & 1;
  int r0, c0, gstride; size_t goff;
  if (tile == 0) { r0 = 0; c0 = 0; goff = G_D1; gstride = 128; }
  else if (tile < 9) { r0 = 0; c0 = 128 * tile; goff = G_D2 + (size_t)(tile - 1) * 128; gstride = 1024; }
  else if (tile < 17) {
    int t2 = tile - 9; int j = t2 >> 1, p = t2 & 1;
    r0 = 128 + 256 * j + 128 * p; c0 = r0;
    goff = G_S + (size_t)j * 65536 + (size_t)p * (128 * 256 + 128); gstride = 256;
  } else {
    int j = tile - 17;
    r0 = 128 + 256 * j; c0 = r0 + 128;
    goff = G_S + (size_t)j * 65536 + 128; gstride = 256;
  }
  const u16* Mb = Mbuf + (size_t)b * 1152 * HW;
  __shared__ u16 As[128][132];
  __shared__ u16 Bs[128][132];
  const int t = threadIdx.x;
  const int lane = t & 63, w = t >> 6;
  const int wr = w >> 1, wc = w & 1;
  const int m = lane & 15, quad = lane >> 4;
  f32x4 acc[4][4];
  #pragma unroll
  for (int i = 0; i < 4; i++)
    #pragma unroll
    for (int j = 0; j < 4; j++) acc[i][j] = (f32x4){0.f, 0.f, 0.f, 0.f};

  for (int s0 = ks * 1024; s0 < ks * 1024 + 1024; s0 += 128) {
    for (int e = t; e < 2048; e += 256) {
      int r = e >> 4, c8 = (e & 15) * 8;
      *(uint4*)&As[r][c8] = *(const uint4*)&Mb[(size_t)(r0 + r) * HW + s0 + c8];
      *(uint4*)&Bs[r][c8] = *(const uint4*)&Mb[(size_t)(c0 + r) * HW + s0 + c8];
    }
    __syncthreads();
    #pragma unroll
    for (int k0 = 0; k0 < 128; k0 += 32) {
      short8 af[4], bf[4];
      #pragma unroll
      for (int i = 0; i < 4; i++) af[i] = *(const short8*)&As[wr * 64 + i * 16 + m][k0 + quad * 8];
      #pragma unroll
      for (int j = 0; j < 4; j++) bf[j] = *(const short8*)&Bs[wc * 64 + j * 16 + m][k0 + quad * 8];
      #pragma unroll
      for (int i = 0; i < 4; i++)
        #pragma unroll
        for (int j = 0; j < 4; j++)
          acc[i][j] = __builtin_amdgcn_mfma_f32_16x16x32_bf16(af[i], bf[j], acc[i][j], 0, 0, 0);
    }
    __syncthreads();
  }
  float* Gb = G + (size_t)b * G_SZ + goff;
  #pragma unroll
  for (int i = 0; i < 4; i++)
    #pragma unroll
    for (int j = 0; j < 4; j++) {
      int col = wc * 64 + j * 16 + m;
      #pragma unroll
      for (int r = 0; r < 4; r++) {
        int row = wr * 64 + i * 16 + quad * 4 + r;
        atomicAdd(&Gb[(size_t)row * gstride + col], acc[i][j][r]);
      }
    }
}

// ------------------------------------- mirror S_j lower-left = upper-right^T
__global__ __launch_bounds__(256) void mirror_S(float* __restrict__ G) {
  const int j = blockIdx.x & 3, b = blockIdx.x >> 2;
  float* base = G + (size_t)b * G_SZ + G_S + (size_t)j * 65536;
  const int t = threadIdx.x;
  for (int e = t; e < 16384; e += 256) {
    int rr = e >> 7, cc = e & 127;
    base[(size_t)(128 + rr) * 256 + cc] = base[(size_t)cc * 256 + 128 + rr];
  }
}

// ------------------------------------------------------------------ Q row inv-norms
__global__ __launch_bounds__(64) void qnorm(
    const u16* __restrict__ qw, const float* __restrict__ G,
    float* __restrict__ invQ) {
  const int bn = blockIdx.x, b = bn >> 2, n = bn & 3;
  const int rq = threadIdx.x;
  const int i = rq & 3, q1r = rq >> 2;
  const u16* qr = qw + ((size_t)(i * 64) + 16 * n + q1r) * 32;
  float v[32];
  #pragma unroll
  for (int c = 0; c < 32; c++) v[c] = b2f(qr[c]);
  const float* D1 = G + (size_t)b * G_SZ;
  float ss = 0.f;
  for (int c = 0; c < 32; c++) {
    float tmp = 0.f;
    #pragma unroll
    for (int c2 = 0; c2 < 32; c2++) tmp = fmaf(v[c2], D1[(size_t)(32 * i + c2) * 128 + 32 * i + c], tmp);
    ss = fmaf(tmp, v[c], ss);
  }
  invQ[bn * 64 + rq] = 1.f / fmaxf(sqrtf(fmaxf(ss, 0.f)), 1e-12f);
}

// ------------------------------------------------------------------ K row inv-norms
__global__ __launch_bounds__(256) void knorm(
    const u16* __restrict__ kw, const float* __restrict__ G,
    float* __restrict__ invK) {
  const int rk = blockIdx.x, n = blockIdx.y, b = blockIdx.z;
  const int j = rk & 3, kk = rk >> 2;
  const u16* kr = kw + ((size_t)(j * 512) + 128 * n + kk) * 256;
  __shared__ float vs[256];
  const int t = threadIdx.x;
  vs[t] = b2f(kr[t]);
  __syncthreads();
  const float* S = G + (size_t)b * G_SZ + G_S + (size_t)j * 65536;
  float tmp = 0.f;
  for (int c2 = 0; c2 < 256; c2++) tmp = fmaf(vs[c2], S[(size_t)c2 * 256 + t], tmp);
  tmp *= vs[t];
  tmp = wave_sum(tmp);
  __shared__ float red[4];
  if ((t & 63) == 0) red[t >> 6] = tmp;
  __syncthreads();
  if (t == 0) {
    float tot = fmaxf(red[0] + red[1] + red[2] + red[3], 0.f);
    invK[(size_t)(b * 4 + n) * 512 + rk] = 1.f / fmaxf(sqrtf(tot), 1e-12f);
  }
}

// ------------------- score2: per (j,n,b): KD = D2_j . kw^T, then blockdiag(q_w).KD
__global__ __launch_bounds__(256) void score2(
    const u16* __restrict__ qw, const u16* __restrict__ kw,
    const float* __restrict__ G, float* __restrict__ score) {
  const int j = blockIdx.x, n = blockIdx.y, b = blockIdx.z;
  const float* D2 = G + (size_t)b * G_SZ + G_D2;
  const u16* kwb = kw + ((size_t)(j * 512) + 128 * n) * 256;
  __shared__ float As[64][132];
  __shared__ u16 Bs[64][128];
  __shared__ float KD[128][132];
  __shared__ float qws[64][32];
  const int t = threadIdx.x, tx = t & 15, ty = t >> 4;
  float acc[8][8];
  #pragma unroll
  for (int i = 0; i < 8; i++)
    #pragma unroll
    for (int jj = 0; jj < 8; jj++) acc[i][jj] = 0.f;
  for (int ch0 = 0; ch0 < 256; ch0 += 64) {
    for (int e = t; e < 8192; e += 256) {
      int r = e >> 6, kc = e & 63;
      As[kc][r] = D2[(size_t)r * 1024 + j * 256 + ch0 + kc];
      Bs[kc][r] = kwb[(size_t)r * 256 + ch0 + kc];
    }
    __syncthreads();
    #pragma unroll 4
    for (int kc = 0; kc < 64; kc++) {
      float4 a0 = *(const float4*)&As[kc][ty * 8];
      float4 a1 = *(const float4*)&As[kc][ty * 8 + 4];
      uint4 bv = *(const uint4*)&Bs[kc][tx * 8];
      float a[8] = {a0.x, a0.y, a0.z, a0.w, a1.x, a1.y, a1.z, a1.w};
      float bb[8];
      unpack8(bv, bb);
      #pragma unroll
      for (int i = 0; i < 8; i++)
        #pragma unroll
        for (int jj = 0; jj < 8; jj++) acc[i][jj] = fmaf(a[i], bb[jj], acc[i][jj]);
    }
    __syncthreads();
  }
  #pragma unroll
  for (int i = 0; i < 8; i++)
    #pragma unroll
    for (int jj = 0; jj < 8; jj++) KD[ty * 8 + i][tx * 8 + jj] = acc[i][jj];
  for (int e = t; e < 2048; e += 256) {
    int q = e >> 5, c = e & 31;
    int i = q & 3, q1r = q >> 2;
    qws[q][c] = b2f(qw[((size_t)(i * 64) + 16 * n + q1r) * 32 + c]);
  }
  __syncthreads();
  float* sb = score + (size_t)(b * 4 + n) * 64 * 512;
  for (int e = t; e < 8192; e += 256) {
    int q = e >> 7, kk = e & 127;
    int i = q & 3;
    float s = 0.f;
    #pragma unroll
    for (int c = 0; c < 32; c++) s = fmaf(qws[q][c], KD[i * 32 + c][kk], s);
    sb[(size_t)q * 512 + 4 * kk + j] = s;
  }
}

// ------------------------------------------ scale + InstanceNorm + row softmax
__global__ __launch_bounds__(256) void in_softmax(
    float* __restrict__ score, const float* __restrict__ invQ,
    const float* __restrict__ invK) {
  const int bn = blockIdx.x;
  float* sb = score + (size_t)bn * 64 * 512;
  const float* iQ = invQ + bn * 64;
  const float* iK = invK + bn * 512;
  const int t = threadIdx.x;
  float sum = 0.f, ss = 0.f;
  const float isc = 1.f / 128.f;
  for (int e = t; e < 32768; e += 256) {
    int q = e >> 9, kk = e & 511;
    float v = sb[e] * iQ[q] * iK[kk] * isc;
    sb[e] = v;
    sum += v; ss += v * v;
  }
  __shared__ float red[8];
  sum = wave_sum(sum); ss = wave_sum(ss);
  if ((t & 63) == 0) { red[t >> 6] = sum; red[4 + (t >> 6)] = ss; }
  __syncthreads();
  float mean = (red[0] + red[1] + red[2] + red[3]) * (1.f / 32768.f);
  float var = (red[4] + red[5] + red[6] + red[7]) * (1.f / 32768.f) - mean * mean;
  float istd = rsqrtf(var + 1e-5f);
  const int wv = t >> 6, lane = t & 63;
  for (int r = wv; r < 64; r += 4) {
    float z[8];
    float m = -1e30f;
    #pragma unroll
    for (int j = 0; j < 8; j++) {
      z[j] = (sb[(size_t)r * 512 + lane + 64 * j] - mean) * istd;
      m = fmaxf(m, z[j]);
    }
    m = wave_max(m);
    float sloc = 0.f;
    #pragma unroll
    for (int j = 0; j < 8; j++) { z[j] = expf(z[j] - m); sloc += z[j]; }
    sloc = wave_sum(sloc);
    float rinv = 1.f / sloc;
    #pragma unroll
    for (int j = 0; j < 8; j++) sb[(size_t)r * 512 + lane + 64 * j] = z[j] * rinv;
  }
}

// ------------------------------------------- W2[bn][q][j*256+ch] = attn . v_w
__global__ __launch_bounds__(256) void attnW2(
    const float* __restrict__ attn, const u16* __restrict__ vw,
    float* __restrict__ W2) {
  const int n = blockIdx.x, q0 = blockIdx.y * 8, b = blockIdx.z, bn = b * 4 + n;
  const float* ab = attn + (size_t)bn * 64 * 512;
  const int t = threadIdx.x;
  const int j = t >> 6, lane = t & 63;
  __shared__ float at_s[8][512];
  for (int e = t; e < 4096; e += 256) {
    int qg = e >> 9, kcol = e & 511;
    at_s[qg][kcol] = ab[(size_t)(q0 + qg) * 512 + kcol];
  }
  __syncthreads();
  float acc[8][4];
  #pragma unroll
  for (int qg = 0; qg < 8; qg++)
    #pragma unroll
    for (int cc = 0; cc < 4; cc++) acc[qg][cc] = 0.f;
  for (int kk = 0; kk < 128; kk++) {
    const u16* vrow = vw + ((size_t)(j * 512) + 128 * n + kk) * 256 + lane;
    float v0 = b2f(vrow[0]), v1 = b2f(vrow[64]), v2 = b2f(vrow[128]), v3 = b2f(vrow[192]);
    #pragma unroll
    for (int qg = 0; qg < 8; qg++) {
      float a = at_s[qg][4 * kk + j];
      acc[qg][0] = fmaf(a, v0, acc[qg][0]);
      acc[qg][1] = fmaf(a, v1, acc[qg][1]);
      acc[qg][2] = fmaf(a, v2, acc[qg][2]);
      acc[qg][3] = fmaf(a, v3, acc[qg][3]);
    }
  }
  #pragma unroll
  for (int qg = 0; qg < 8; qg++)
    #pragma unroll
    for (int cc = 0; cc < 4; cc++)
      W2[((size_t)bn * 64 + q0 + qg) * 1024 + j * 256 + lane + 64 * cc] = acc[qg][cc];
}

// ------------------------------------------ Wfin16[b][o][jc] = bf16(out_w . W2)
__global__ __launch_bounds__(256) void wfin_k(
    const u16* __restrict__ ow, const float* __restrict__ W2,
    u16* __restrict__ Wfin16) {
  const int jc = blockIdx.x, b = blockIdx.y;
  __shared__ float col[256];
  const int t = threadIdx.x;
  col[t] = W2[((size_t)b * 256 + t) * 1024 + jc];
  __syncthreads();
  float acc = 0.f;
  const u16* owr = ow + (size_t)t * 256;
  for (int c = 0; c < 256; c++) acc = fmaf(b2f(owr[c]), col[c], acc);
  Wfin16[((size_t)b * 256 + t) * 1024 + jc] = f2b(acc);
}

// -------------------------------------- y = Wfin(bf16) @ sur via MFMA (bf16 out)
__global__ __launch_bounds__(256) void y_gemm_mfma(
    const u16* __restrict__ Wfin16, const u16* __restrict__ Mbuf,
    u16* __restrict__ ybuf) {
  const int b = blockIdx.z, row0 = blockIdx.y * 128, col0 = blockIdx.x * 128;
  __shared__ u16 As[128][72];
  __shared__ u16 Bs[128][72];
  const u16* Ab = Wfin16 + (size_t)b * 256 * 1024;
  const u16* Mb = Mbuf + (size_t)b * 1152 * HW + (size_t)128 * HW;
  const int t = threadIdx.x;
  const int lane = t & 63, w = t >> 6;
  const int wr = w >> 1, wc = w & 1;
  const int m = lane & 15, quad = lane >> 4;
  f32x4 acc[4][4];
  #pragma unroll
  for (int i = 0; i < 4; i++)
    #pragma unroll
    for (int j = 0; j < 4; j++) acc[i][j] = (f32x4){0.f, 0.f, 0.f, 0.f};

  for (int k0c = 0; k0c < 1024; k0c += 64) {
    for (int e = t; e < 1024; e += 256) {
      int r = e >> 3, kc8 = (e & 7) * 8;
      *(uint4*)&As[r][kc8] = *(const uint4*)&Ab[(size_t)(row0 + r) * 1024 + k0c + kc8];
    }
    for (int e = t; e < 1024; e += 256) {
      int kc = e >> 4, c8 = (e & 15) * 8;
      uint4 v = *(const uint4*)&Mb[(size_t)(k0c + kc) * HW + col0 + c8];
      u16 tmp[8]; *(uint4*)tmp = v;
      #pragma unroll
      for (int uu = 0; uu < 8; uu++) {
        int u = (uu + lane) & 7;
        Bs[c8 + u][kc] = tmp[u];
      }
    }
    __syncthreads();
    #pragma unroll
    for (int k0 = 0; k0 < 64; k0 += 32) {
      short8 af[4], bf[4];
      #pragma unroll
      for (int i = 0; i < 4; i++) af[i] = *(const short8*)&As[wr * 64 + i * 16 + m][k0 + quad * 8];
      #pragma unroll
      for (int j = 0; j < 4; j++) bf[j] = *(const short8*)&Bs[wc * 64 + j * 16 + m][k0 + quad * 8];
      #pragma unroll
      for (int i = 0; i < 4; i++)
        #pragma unroll
        for (int j = 0; j < 4; j++)
          acc[i][j] = __builtin_amdgcn_mfma_f32_16x16x32_bf16(af[i], bf[j], acc[i][j], 0, 0, 0);
    }
    __syncthreads();
  }
  #pragma unroll
  for (int i = 0; i < 4; i++)
    #pragma unroll
    for (int j = 0; j < 4; j++) {
      int col = col0 + wc * 64 + j * 16 + m;
      #pragma unroll
      for (int r = 0; r < 4; r++) {
        int row = row0 + wr * 64 + i * 16 + quad * 4 + r;
        ybuf[((size_t)b * 256 + row) * HW + col] = f2b(acc[i][j][r]);
      }
    }
}

// ---------------------------------------------------------------- BatchNorm
__global__ __launch_bounds__(256) void bn_stats(
    const u16* __restrict__ y, float* __restrict__ st) {
  const int o = blockIdx.x;
  const int t = threadIdx.x;
  float sum = 0.f, ss = 0.f;
  for (int bb = 0; bb < 2; bb++) {
    const u16* p = y + ((size_t)bb * 256 + o) * HW;
    for (int e = t; e < HW / 8; e += 256) {
      uint4 v = ((const uint4*)p)[e];
      float f[8];
      unpack8(v, f);
      #pragma unroll
      for (int k = 0; k < 8; k++) { sum += f[k]; ss += f[k] * f[k]; }
    }
  }
  __shared__ float red[8];
  sum = wave_sum(sum); ss = wave_sum(ss);
  if ((t & 63) == 0) { red[t >> 6] = sum; red[4 + (t >> 6)] = ss; }
  __syncthreads();
  if (t == 0) {
    float mean = (red[0] + red[1] + red[2] + red[3]) / 32768.f;
    float var = (red[4] + red[5] + red[6] + red[7]) / 32768.f - mean * mean;
    st[o * 2] = mean;
    st[o * 2 + 1] = rsqrtf(var + 1e-5f);
  }
}

__global__ __launch_bounds__(256) void bn_apply(
    const u16* __restrict__ y, const float* __restrict__ st,
    const u16* __restrict__ gamma, const u16* __restrict__ beta,
    const int* __restrict__ flag, void* __restrict__ out) {
  const int idx8 = blockIdx.x * 256 + threadIdx.x;
  const int r = idx8 >> 11;
  const int o = r & 255;
  float mean = st[o * 2], istd = st[o * 2 + 1];
  float g = b2f(gamma[o]), be = b2f(beta[o]);
  uint4 v = ((const uint4*)y)[idx8];
  float f[8];
  unpack8(v, f);
  float rr[8];
  #pragma unroll
  for (int k = 0; k < 8; k++) rr[k] = fmaxf((f[k] - mean) * istd * g + be, 0.f);
  if (*flag) {
    float* of = (float*)out + (size_t)idx8 * 8;
    *(float4*)of = make_float4(rr[0], rr[1], rr[2], rr[3]);
    *(float4*)(of + 4) = make_float4(rr[4], rr[5], rr[6], rr[7]);
  } else {
    u32 p0 = (u32)f2b(rr[0]) | ((u32)f2b(rr[1]) << 16);
    u32 p1 = (u32)f2b(rr[2]) | ((u32)f2b(rr[3]) << 16);
    u32 p2 = (u32)f2b(rr[4]) | ((u32)f2b(rr[5]) << 16);
    u32 p3 = (u32)f2b(rr[6]) | ((u32)f2b(rr[7]) << 16);
    ((uint4*)out)[idx8] = make_uint4(p0, p1, p2, p3);
  }
}

// ----------------------------------------------------------------------------
extern "C" void kernel_launch(void* const* d_in, const int* in_sizes, int n_in,
                              void* d_out, int out_size, void* d_ws, size_t ws_size,
                              hipStream_t stream) {
  float* G     = (float*)d_ws;           // 819,200 f32 (2 x G_SZ)
  float* score = G + 819200;             // 262,144
  float* invQ  = score + 262144;         // 512
  float* invK  = invQ + 512;             // 4,096
  float* W2    = invK + 4096;            // 524,288
  float* Wfin  = W2 + 524288;            // slot reused: u16 Wfin16
  float* bnst  = Wfin + 524288;          // 512
  int* flag    = (int*)(bnst + 512);     // 16
  u16* Sbuf    = (u16*)(flag + 16);      // S_TOTAL u16
  u16* Mbuf    = Sbuf + S_TOTAL;         // 37,748,736 u16
  u16* ybuf    = Mbuf + 37748736;        // 8,388,608 u16
  u16* Wfin16  = (u16*)Wfin;
  float* lgbuf = (float*)ybuf;           // alias: lgbuf (4MB) consumed before y_gemm writes ybuf

  probe<<<1, 64, 0, stream>>>((const u32*)d_in[10], flag);
  convert_all<<<dim3(1024, 1, 12), 256, 0, stream>>>(
      d_in[0], d_in[1], d_in[2], d_in[3], d_in[4], d_in[5], d_in[6], d_in[7],
      d_in[8], d_in[9], d_in[10], d_in[11], Sbuf, flag);

  sur_w<<<dim3(64, 2, 4), 256, 0, stream>>>(
      Sbuf + S_CEN, Sbuf + S_W1, Sbuf + S_B1, Sbuf + S_W2, Sbuf + S_B2,
      Sbuf + S_SW, lgbuf);
  sur_scatter<<<dim3(32, 4, 8), 256, 0, stream>>>(
      Sbuf + S_CEN, lgbuf, Sbuf + S_SW, Mbuf);
  hipMemsetAsync(G, 0, 819200 * sizeof(float), stream);
  gram_mfma<<<672, 256, 0, stream>>>(Mbuf, G);
  mirror_S<<<8, 256, 0, stream>>>(G);
  qnorm<<<8, 64, 0, stream>>>(Sbuf + S_QW, G, invQ);
  knorm<<<dim3(512, 4, 2), 256, 0, stream>>>(Sbuf + S_KW, G, invK);
  score2<<<dim3(4, 4, 2), 256, 0, stream>>>(Sbuf + S_QW, Sbuf + S_KW, G, score);
  in_softmax<<<8, 256, 0, stream>>>(score, invQ, invK);
  attnW2<<<dim3(4, 8, 2), 256, 0, stream>>>(score, Sbuf + S_VW, W2);
  wfin_k<<<dim3(1024, 2), 256, 0, stream>>>(Sbuf + S_OW, W2, Wfin16);
  y_gemm_mfma<<<dim3(128, 2, 2), 256, 0, stream>>>(Wfin16, Mbuf, ybuf);
  bn_stats<<<256, 256, 0, stream>>>(ybuf, bnst);
  bn_apply<<<4096, 256, 0, stream>>>(ybuf, bnst, Sbuf + S_GAMMA, Sbuf + S_BETA,
                                     flag, d_out);
}

// Round 8
// 555.528 us; speedup vs baseline: 1.1507x; 1.0716x over previous
//
#include <hip/hip_runtime.h>

// Gram-trick + MFMA. Ladder: 2310 -> 1380 -> 626 -> 639 -> 595.
// R8: gram BK=64 (36.8KB LDS -> 4 blk/CU; R7's 67.5KB gave only 2 -> latency-bound
// at 1.34TB/s despite FETCH ~= unique bytes); score2 kk-split x2 (32 -> 64 blocks).

#define HW 16384
typedef unsigned short u16;
typedef unsigned int u32;
typedef __attribute__((ext_vector_type(8))) short short8;
typedef __attribute__((ext_vector_type(4))) float f32x4;

// staging offsets (u16 elements)
#define S_CEN 0
#define S_QW 1048576
#define S_KW 1056768
#define S_VW 1581056
#define S_W1 2105344
#define S_B1 2142208
#define S_W2 2142336
#define S_B2 2143360
#define S_SW 2143392
#define S_OW 2143400
#define S_GAMMA 2208936
#define S_BETA 2209192
#define S_TOTAL 2209456

// compact Gram layout per batch (f32 elements)
#define G_D1 0       // 128x128, stride 128
#define G_D2 16384   // 128x1024, stride 1024
#define G_S 147456   // 4 blocks of 256x256, stride 256
#define G_SZ 409600

__device__ __forceinline__ float b2f(u16 u) { return __uint_as_float(((u32)u) << 16); }
__device__ __forceinline__ u16 f2b(float f) {
  u32 u = __float_as_uint(f);
  return (u16)((u + 0x7FFFu + ((u >> 16) & 1u)) >> 16);  // RNE
}
__device__ __forceinline__ float wave_sum(float v) {
  #pragma unroll
  for (int off = 32; off > 0; off >>= 1) v += __shfl_xor(v, off, 64);
  return v;
}
__device__ __forceinline__ float wave_max(float v) {
  #pragma unroll
  for (int off = 32; off > 0; off >>= 1) v = fmaxf(v, __shfl_xor(v, off, 64));
  return v;
}
__device__ __forceinline__ void unpack8(uint4 v, float* f) {
  f[0] = __uint_as_float(v.x << 16); f[1] = __uint_as_float(v.x & 0xFFFF0000u);
  f[2] = __uint_as_float(v.y << 16); f[3] = __uint_as_float(v.y & 0xFFFF0000u);
  f[4] = __uint_as_float(v.z << 16); f[5] = __uint_as_float(v.z & 0xFFFF0000u);
  f[6] = __uint_as_float(v.w << 16); f[7] = __uint_as_float(v.w & 0xFFFF0000u);
}

// ------------------------------------------------------------ dtype probe
__global__ void probe(const u32* __restrict__ g, int* __restrict__ flag) {
  if (threadIdx.x == 0) {
    int ok = 1;
    #pragma unroll
    for (int i = 0; i < 4; i++) {
      u32 w = g[i];
      u32 lo = w & 0xFFFFu, hi = w >> 16;
      ok &= (lo >= 0x3E00u && lo <= 0x4100u) ? 1 : 0;
      ok &= (hi >= 0x3E00u && hi <= 0x4100u) ? 1 : 0;
    }
    *flag = ok ? 0 : 1;  // 0 = bf16 inputs, 1 = f32 inputs
  }
}

// ------------------------------------------------------------ stage inputs -> bf16
__global__ __launch_bounds__(256) void convert_all(
    const void* p0, const void* p1, const void* p2, const void* p3,
    const void* p4, const void* p5, const void* p6, const void* p7,
    const void* p8, const void* p9, const void* p10, const void* p11,
    u16* __restrict__ S, const int* __restrict__ flag) {
  const void* src; int n; int off;
  switch (blockIdx.z) {
    case 0:  src = p0;  n = 1048576; off = S_CEN; break;
    case 1:  src = p1;  n = 8192;    off = S_QW; break;
    case 2:  src = p2;  n = 524288;  off = S_KW; break;
    case 3:  src = p3;  n = 524288;  off = S_VW; break;
    case 4:  src = p4;  n = 36864;   off = S_W1; break;
    case 5:  src = p5;  n = 128;     off = S_B1; break;
    case 6:  src = p6;  n = 1024;    off = S_W2; break;
    case 7:  src = p7;  n = 32;      off = S_B2; break;
    case 8:  src = p8;  n = 8;       off = S_SW; break;
    case 9:  src = p9;  n = 65536;   off = S_OW; break;
    case 10: src = p10; n = 256;     off = S_GAMMA; break;
    default: src = p11; n = 256;     off = S_BETA; break;
  }
  int idx = (blockIdx.x * 256 + threadIdx.x) * 4;
  if (idx >= n) return;
  u16* dst = S + off + idx;
  if (*flag) {
    float4 v = ((const float4*)src)[idx >> 2];
    dst[0] = f2b(v.x); dst[1] = f2b(v.y); dst[2] = f2b(v.z); dst[3] = f2b(v.w);
  } else {
    *(ushort4*)dst = ((const ushort4*)src)[idx >> 2];
  }
}

// ------------------- sur_w: conv + 8-way softmax weights -> lgbuf[b][si][s][8] f32
__global__ __launch_bounds__(256) void sur_w(
    const u16* __restrict__ cen, const u16* __restrict__ w1g,
    const u16* __restrict__ b1g, const u16* __restrict__ w2g,
    const u16* __restrict__ b2g, const u16* __restrict__ swg,
    float* __restrict__ lgbuf) {
  const int si = blockIdx.z;
  const int d = 1 << si;
  __shared__ float w1s[9216];  // [tap][ci][co]
  __shared__ float w2s[256];
  __shared__ float b1s[32];
  __shared__ float b2s[8];
  const int t = threadIdx.x;
  for (int e = t; e < 9216; e += 256) {
    int tap = e >> 10, rem = e & 1023, ci = rem >> 5, co = rem & 31;
    w1s[e] = b2f(w1g[si * 9216 + co * 288 + ci * 9 + tap]);
  }
  w2s[t] = b2f(w2g[si * 256 + t]);
  if (t < 32) b1s[t] = b2f(b1g[si * 32 + t]);
  if (t < 8) b2s[t] = b2f(b2g[si * 8 + t]);
  __syncthreads();

  const int b = blockIdx.y;
  const int s = blockIdx.x * 256 + t;
  const int h = s >> 7, w = s & 127;

  float s0 = b2f(swg[si * 2 + 0]), s1 = b2f(swg[si * 2 + 1]);
  float mx = fmaxf(s0, s1);
  float e0 = expf(s0 - mx), e1 = expf(s1 - mx);
  float w20 = e0 / (e0 + e1);

  const u16* cb = cen + (size_t)b * 32 * HW;

  float h1[32];
  #pragma unroll
  for (int i = 0; i < 32; i++) h1[i] = 0.f;
  for (int tap = 0; tap < 9; tap++) {
    int ky = tap / 3, kx = tap - ky * 3;
    int y = h + (ky - 1) * d, x = w + (kx - 1) * d;
    if (y < 0 || y >= 128 || x < 0 || x >= 128) continue;
    int off = y * 128 + x;
    const float* wt = &w1s[tap * 1024];
    for (int ci = 0; ci < 32; ci++) {
      float v = b2f(cb[(size_t)ci * HW + off]);
      #pragma unroll
      for (int co = 0; co < 32; co++) h1[co] = fmaf(v, wt[ci * 32 + co], h1[co]);
    }
  }
  #pragma unroll
  for (int i = 0; i < 32; i++) h1[i] = fmaxf(h1[i] + b1s[i], 0.f);

  float lg[8];
  #pragma unroll
  for (int k = 0; k < 8; k++) lg[k] = b2s[k];
  for (int ci = 0; ci < 32; ci++) {
    float v = h1[ci];
    #pragma unroll
    for (int k = 0; k < 8; k++) lg[k] = fmaf(v, w2s[k * 32 + ci], lg[k]);
  }
  float lm = lg[0];
  #pragma unroll
  for (int k = 1; k < 8; k++) lm = fmaxf(lm, lg[k]);
  float ls = 0.f;
  #pragma unroll
  for (int k = 0; k < 8; k++) { lg[k] = expf(lg[k] - lm); ls += lg[k]; }
  float inv = w20 / ls;
  float* lp = lgbuf + ((size_t)(b * 4 + si) * HW + s) * 8;
  *(float4*)lp = make_float4(lg[0] * inv, lg[1] * inv, lg[2] * inv, lg[3] * inv);
  *(float4*)(lp + 4) = make_float4(lg[4] * inv, lg[5] * inv, lg[6] * inv, lg[7] * inv);
}

// ------------- sur_scatter: neighbors + sumx/cenx/sur writes (2px, 8ch per thread)
__global__ __launch_bounds__(256) void sur_scatter(
    const u16* __restrict__ cen, const float* __restrict__ lgbuf,
    const u16* __restrict__ swg, u16* __restrict__ Mbuf) {
  const int z = blockIdx.z;
  const int b = z >> 2, si = z & 3, d = 1 << si;
  const int c0 = blockIdx.y * 8;
  const int t = threadIdx.x;
  const int s = (blockIdx.x * 256 + t) * 2;  // even
  const int h = s >> 7, w = s & 127;

  float s0 = b2f(swg[si * 2 + 0]), s1 = b2f(swg[si * 2 + 1]);
  float mx = fmaxf(s0, s1);
  float e0 = expf(s0 - mx), e1 = expf(s1 - mx);
  float w20 = e0 / (e0 + e1), w21 = e1 / (e0 + e1);

  const float* lpa = lgbuf + ((size_t)(b * 4 + si) * HW + s) * 8;
  float4 la0 = *(const float4*)lpa, la1 = *(const float4*)(lpa + 4);
  float4 lb0 = *(const float4*)(lpa + 8), lb1 = *(const float4*)(lpa + 12);
  float lga[8] = {la0.x, la0.y, la0.z, la0.w, la1.x, la1.y, la1.z, la1.w};
  float lgb[8] = {lb0.x, lb0.y, lb0.z, lb0.w, lb1.x, lb1.y, lb1.z, lb1.w};

  const int dy[8] = {-d, -d, -d, 0, 0, d, d, d};
  const int dx[8] = {-d, 0, d, -d, d, -d, 0, d};
  int offa[8], offb[8];
  #pragma unroll
  for (int k = 0; k < 8; k++) {
    int y = h + dy[k]; y = y < 0 ? -y : (y > 127 ? 254 - y : y);
    int xa = w + dx[k]; xa = xa < 0 ? -xa : (xa > 127 ? 254 - xa : xa);
    int xb = w + 1 + dx[k]; xb = xb < 0 ? -xb : (xb > 127 ? 254 - xb : xb);
    offa[k] = y * 128 + xa;
    offb[k] = y * 128 + xb;
  }
  const u16* cb = cen + (size_t)b * 32 * HW;
  u16* Mb = Mbuf + (size_t)b * 1152 * HW;
  for (int c = c0; c < c0 + 8; c++) {
    const u16* cc = cb + (size_t)c * HW;
    u32 cvp = *(const u32*)&cc[s];
    float cva = __uint_as_float(cvp << 16), cvb = __uint_as_float(cvp & 0xFFFF0000u);
    float nba[8], nbb[8];
    #pragma unroll
    for (int k = 0; k < 8; k++) { nba[k] = b2f(cc[offa[k]]); nbb[k] = b2f(cc[offb[k]]); }
    float sxa = 0.f, mna = 0.f, sxb = 0.f, mnb = 0.f;
    #pragma unroll
    for (int k = 0; k < 8; k++) {
      sxa = fmaf(lga[k], nba[k], sxa); mna += nba[k];
      sxb = fmaf(lgb[k], nbb[k], sxb); mnb += nbb[k];
    }
    float suma = sxa + cva * w21, sumb = sxb + cvb * w21;
    u32 cx = (u32)f2b(mna * 0.125f * w20 + cva * w21) |
             ((u32)f2b(mnb * 0.125f * w20 + cvb * w21) << 16);
    *(u32*)&Mb[(size_t)(32 * si + c) * HW + s] = cx;
    #pragma unroll
    for (int k = 0; k < 8; k++) {
      u32 pk = (u32)f2b(nba[k] - suma) | ((u32)f2b(nbb[k] - sumb) << 16);
      *(u32*)&Mb[(size_t)(128 + 256 * si + k * 32 + c) * HW + s] = pk;
    }
  }
}

// ------------ Gram via MFMA: BK=64 (4 blk/CU), 21 tiles, XCD-combo swizzle, atomics
__global__ __launch_bounds__(256) void gram_mfma(
    const u16* __restrict__ Mbuf, float* __restrict__ G) {
  const int id = blockIdx.x;
  const int tile = id >> 5, combo = id & 31;
  const int ks = combo >> 1, b = combo & 1;
  int r0, c0, gstride; size_t goff;
  if (tile == 0) { r0 = 0; c0 = 0; goff = G_D1; gstride = 128; }
  else if (tile < 9) { r0 = 0; c0 = 128 * tile; goff = G_D2 + (size_t)(tile - 1) * 128; gstride = 1024; }
  else if (tile < 17) {
    int t2 = tile - 9; int j = t2 >> 1, p = t2 & 1;
    r0 = 128 + 256 * j + 128 * p; c0 = r0;
    goff = G_S + (size_t)j * 65536 + (size_t)p * (128 * 256 + 128); gstride = 256;
  } else {
    int j = tile - 17;
    r0 = 128 + 256 * j; c0 = r0 + 128;
    goff = G_S + (size_t)j * 65536 + 128; gstride = 256;
  }
  const u16* Mb = Mbuf + (size_t)b * 1152 * HW;
  __shared__ u16 As[128][72];
  __shared__ u16 Bs[128][72];
  const int t = threadIdx.x;
  const int lane = t & 63, w = t >> 6;
  const int wr = w >> 1, wc = w & 1;
  const int m = lane & 15, quad = lane >> 4;
  f32x4 acc[4][4];
  #pragma unroll
  for (int i = 0; i < 4; i++)
    #pragma unroll
    for (int j = 0; j < 4; j++) acc[i][j] = (f32x4){0.f, 0.f, 0.f, 0.f};

  for (int s0 = ks * 1024; s0 < ks * 1024 + 1024; s0 += 64) {
    for (int e = t; e < 1024; e += 256) {
      int r = e >> 3, c8 = (e & 7) * 8;
      *(uint4*)&As[r][c8] = *(const uint4*)&Mb[(size_t)(r0 + r) * HW + s0 + c8];
      *(uint4*)&Bs[r][c8] = *(const uint4*)&Mb[(size_t)(c0 + r) * HW + s0 + c8];
    }
    __syncthreads();
    #pragma unroll
    for (int k0 = 0; k0 < 64; k0 += 32) {
      short8 af[4], bf[4];
      #pragma unroll
      for (int i = 0; i < 4; i++) af[i] = *(const short8*)&As[wr * 64 + i * 16 + m][k0 + quad * 8];
      #pragma unroll
      for (int j = 0; j < 4; j++) bf[j] = *(const short8*)&Bs[wc * 64 + j * 16 + m][k0 + quad * 8];
      #pragma unroll
      for (int i = 0; i < 4; i++)
        #pragma unroll
        for (int j = 0; j < 4; j++)
          acc[i][j] = __builtin_amdgcn_mfma_f32_16x16x32_bf16(af[i], bf[j], acc[i][j], 0, 0, 0);
    }
    __syncthreads();
  }
  float* Gb = G + (size_t)b * G_SZ + goff;
  #pragma unroll
  for (int i = 0; i < 4; i++)
    #pragma unroll
    for (int j = 0; j < 4; j++) {
      int col = wc * 64 + j * 16 + m;
      #pragma unroll
      for (int r = 0; r < 4; r++) {
        int row = wr * 64 + i * 16 + quad * 4 + r;
        atomicAdd(&Gb[(size_t)row * gstride + col], acc[i][j][r]);
      }
    }
}

// ------------------------------------- mirror S_j lower-left = upper-right^T
__global__ __launch_bounds__(256) void mirror_S(float* __restrict__ G) {
  const int j = blockIdx.x & 3, b = blockIdx.x >> 2;
  float* base = G + (size_t)b * G_SZ + G_S + (size_t)j * 65536;
  const int t = threadIdx.x;
  for (int e = t; e < 16384; e += 256) {
    int rr = e >> 7, cc = e & 127;
    base[(size_t)(128 + rr) * 256 + cc] = base[(size_t)cc * 256 + 128 + rr];
  }
}

// ------------------------------------------------------------------ Q row inv-norms
__global__ __launch_bounds__(64) void qnorm(
    const u16* __restrict__ qw, const float* __restrict__ G,
    float* __restrict__ invQ) {
  const int bn = blockIdx.x, b = bn >> 2, n = bn & 3;
  const int rq = threadIdx.x;
  const int i = rq & 3, q1r = rq >> 2;
  const u16* qr = qw + ((size_t)(i * 64) + 16 * n + q1r) * 32;
  float v[32];
  #pragma unroll
  for (int c = 0; c < 32; c++) v[c] = b2f(qr[c]);
  const float* D1 = G + (size_t)b * G_SZ;
  float ss = 0.f;
  for (int c = 0; c < 32; c++) {
    float tmp = 0.f;
    #pragma unroll
    for (int c2 = 0; c2 < 32; c2++) tmp = fmaf(v[c2], D1[(size_t)(32 * i + c2) * 128 + 32 * i + c], tmp);
    ss = fmaf(tmp, v[c], ss);
  }
  invQ[bn * 64 + rq] = 1.f / fmaxf(sqrtf(fmaxf(ss, 0.f)), 1e-12f);
}

// ------------------------------------------------------------------ K row inv-norms
__global__ __launch_bounds__(256) void knorm(
    const u16* __restrict__ kw, const float* __restrict__ G,
    float* __restrict__ invK) {
  const int rk = blockIdx.x, n = blockIdx.y, b = blockIdx.z;
  const int j = rk & 3, kk = rk >> 2;
  const u16* kr = kw + ((size_t)(j * 512) + 128 * n + kk) * 256;
  __shared__ float vs[256];
  const int t = threadIdx.x;
  vs[t] = b2f(kr[t]);
  __syncthreads();
  const float* S = G + (size_t)b * G_SZ + G_S + (size_t)j * 65536;
  float tmp = 0.f;
  for (int c2 = 0; c2 < 256; c2++) tmp = fmaf(vs[c2], S[(size_t)c2 * 256 + t], tmp);
  tmp *= vs[t];
  tmp = wave_sum(tmp);
  __shared__ float red[4];
  if ((t & 63) == 0) red[t >> 6] = tmp;
  __syncthreads();
  if (t == 0) {
    float tot = fmaxf(red[0] + red[1] + red[2] + red[3], 0.f);
    invK[(size_t)(b * 4 + n) * 512 + rk] = 1.f / fmaxf(sqrtf(tot), 1e-12f);
  }
}

// ---------- score2 (kk-split x2): per (j,half,n,b): KD = D2_j . kw_half^T, then q_w.KD
__global__ __launch_bounds__(256) void score2(
    const u16* __restrict__ qw, const u16* __restrict__ kw,
    const float* __restrict__ G, float* __restrict__ score) {
  const int jj = blockIdx.x;        // 0..7
  const int j = jj >> 1, half = jj & 1;
  const int n = blockIdx.y, b = blockIdx.z;
  const float* D2 = G + (size_t)b * G_SZ + G_D2;
  const u16* kwb = kw + ((size_t)(j * 512) + 128 * n + half * 64) * 256;  // 64 rows
  __shared__ float As[64][132];  // As[kc][r] = D2[r][j*256+ch0+kc], r<128
  __shared__ u16 Bs[64][68];     // Bs[kc][kk] = kwb[kk][ch0+kc], kk<64
  __shared__ float KD[128][68];  // KD[r][kk]
  __shared__ float qws[64][32];
  const int t = threadIdx.x;
  const int tx = t & 7, ty = t >> 3;  // tx: 8 kk-groups of 8; ty: 32 r-groups of 4
  float acc[4][8];
  #pragma unroll
  for (int i = 0; i < 4; i++)
    #pragma unroll
    for (int u = 0; u < 8; u++) acc[i][u] = 0.f;
  for (int ch0 = 0; ch0 < 256; ch0 += 64) {
    for (int e = t; e < 8192; e += 256) {
      int r = e >> 6, kc = e & 63;
      As[kc][r] = D2[(size_t)r * 1024 + j * 256 + ch0 + kc];
    }
    for (int e = t; e < 4096; e += 256) {
      int r = e >> 6, kc = e & 63;
      Bs[kc][r] = kwb[(size_t)r * 256 + ch0 + kc];
    }
    __syncthreads();
    #pragma unroll 4
    for (int kc = 0; kc < 64; kc++) {
      float a[4];
      #pragma unroll
      for (int i = 0; i < 4; i++) a[i] = As[kc][ty * 4 + i];
      float bb[8];
      #pragma unroll
      for (int u = 0; u < 8; u++) bb[u] = b2f(Bs[kc][tx * 8 + u]);
      #pragma unroll
      for (int i = 0; i < 4; i++)
        #pragma unroll
        for (int u = 0; u < 8; u++) acc[i][u] = fmaf(a[i], bb[u], acc[i][u]);
    }
    __syncthreads();
  }
  #pragma unroll
  for (int i = 0; i < 4; i++)
    #pragma unroll
    for (int u = 0; u < 8; u++) KD[ty * 4 + i][tx * 8 + u] = acc[i][u];
  for (int e = t; e < 2048; e += 256) {
    int q = e >> 5, c = e & 31;
    int i = q & 3, q1r = q >> 2;
    qws[q][c] = b2f(qw[((size_t)(i * 64) + 16 * n + q1r) * 32 + c]);
  }
  __syncthreads();
  float* sb = score + (size_t)(b * 4 + n) * 64 * 512;
  for (int e = t; e < 4096; e += 256) {
    int q = e >> 6, kkl = e & 63;
    int i = q & 3;
    float s = 0.f;
    #pragma unroll
    for (int c = 0; c < 32; c++) s = fmaf(qws[q][c], KD[i * 32 + c][kkl], s);
    sb[(size_t)q * 512 + 4 * (half * 64 + kkl) + j] = s;
  }
}

// ------------------------------------------ scale + InstanceNorm + row softmax
__global__ __launch_bounds__(256) void in_softmax(
    float* __restrict__ score, const float* __restrict__ invQ,
    const float* __restrict__ invK) {
  const int bn = blockIdx.x;
  float* sb = score + (size_t)bn * 64 * 512;
  const float* iQ = invQ + bn * 64;
  const float* iK = invK + bn * 512;
  const int t = threadIdx.x;
  float sum = 0.f, ss = 0.f;
  const float isc = 1.f / 128.f;
  for (int e = t; e < 32768; e += 256) {
    int q = e >> 9, kk = e & 511;
    float v = sb[e] * iQ[q] * iK[kk] * isc;
    sb[e] = v;
    sum += v; ss += v * v;
  }
  __shared__ float red[8];
  sum = wave_sum(sum); ss = wave_sum(ss);
  if ((t & 63) == 0) { red[t >> 6] = sum; red[4 + (t >> 6)] = ss; }
  __syncthreads();
  float mean = (red[0] + red[1] + red[2] + red[3]) * (1.f / 32768.f);
  float var = (red[4] + red[5] + red[6] + red[7]) * (1.f / 32768.f) - mean * mean;
  float istd = rsqrtf(var + 1e-5f);
  const int wv = t >> 6, lane = t & 63;
  for (int r = wv; r < 64; r += 4) {
    float z[8];
    float m = -1e30f;
    #pragma unroll
    for (int j = 0; j < 8; j++) {
      z[j] = (sb[(size_t)r * 512 + lane + 64 * j] - mean) * istd;
      m = fmaxf(m, z[j]);
    }
    m = wave_max(m);
    float sloc = 0.f;
    #pragma unroll
    for (int j = 0; j < 8; j++) { z[j] = expf(z[j] - m); sloc += z[j]; }
    sloc = wave_sum(sloc);
    float rinv = 1.f / sloc;
    #pragma unroll
    for (int j = 0; j < 8; j++) sb[(size_t)r * 512 + lane + 64 * j] = z[j] * rinv;
  }
}

// ------------------------------------------- W2[bn][q][j*256+ch] = attn . v_w
__global__ __launch_bounds__(256) void attnW2(
    const float* __restrict__ attn, const u16* __restrict__ vw,
    float* __restrict__ W2) {
  const int n = blockIdx.x, q0 = blockIdx.y * 8, b = blockIdx.z, bn = b * 4 + n;
  const float* ab = attn + (size_t)bn * 64 * 512;
  const int t = threadIdx.x;
  const int j = t >> 6, lane = t & 63;
  __shared__ float at_s[8][512];
  for (int e = t; e < 4096; e += 256) {
    int qg = e >> 9, kcol = e & 511;
    at_s[qg][kcol] = ab[(size_t)(q0 + qg) * 512 + kcol];
  }
  __syncthreads();
  float acc[8][4];
  #pragma unroll
  for (int qg = 0; qg < 8; qg++)
    #pragma unroll
    for (int cc = 0; cc < 4; cc++) acc[qg][cc] = 0.f;
  for (int kk = 0; kk < 128; kk++) {
    const u16* vrow = vw + ((size_t)(j * 512) + 128 * n + kk) * 256 + lane;
    float v0 = b2f(vrow[0]), v1 = b2f(vrow[64]), v2 = b2f(vrow[128]), v3 = b2f(vrow[192]);
    #pragma unroll
    for (int qg = 0; qg < 8; qg++) {
      float a = at_s[qg][4 * kk + j];
      acc[qg][0] = fmaf(a, v0, acc[qg][0]);
      acc[qg][1] = fmaf(a, v1, acc[qg][1]);
      acc[qg][2] = fmaf(a, v2, acc[qg][2]);
      acc[qg][3] = fmaf(a, v3, acc[qg][3]);
    }
  }
  #pragma unroll
  for (int qg = 0; qg < 8; qg++)
    #pragma unroll
    for (int cc = 0; cc < 4; cc++)
      W2[((size_t)bn * 64 + q0 + qg) * 1024 + j * 256 + lane + 64 * cc] = acc[qg][cc];
}

// ------------------------------------------ Wfin16[b][o][jc] = bf16(out_w . W2)
__global__ __launch_bounds__(256) void wfin_k(
    const u16* __restrict__ ow, const float* __restrict__ W2,
    u16* __restrict__ Wfin16) {
  const int jc = blockIdx.x, b = blockIdx.y;
  __shared__ float col[256];
  const int t = threadIdx.x;
  col[t] = W2[((size_t)b * 256 + t) * 1024 + jc];
  __syncthreads();
  float acc = 0.f;
  const u16* owr = ow + (size_t)t * 256;
  for (int c = 0; c < 256; c++) acc = fmaf(b2f(owr[c]), col[c], acc);
  Wfin16[((size_t)b * 256 + t) * 1024 + jc] = f2b(acc);
}

// -------------------------------------- y = Wfin(bf16) @ sur via MFMA (bf16 out)
__global__ __launch_bounds__(256) void y_gemm_mfma(
    const u16* __restrict__ Wfin16, const u16* __restrict__ Mbuf,
    u16* __restrict__ ybuf) {
  const int b = blockIdx.z, row0 = blockIdx.y * 128, col0 = blockIdx.x * 128;
  __shared__ u16 As[128][72];
  __shared__ u16 Bs[128][72];
  const u16* Ab = Wfin16 + (size_t)b * 256 * 1024;
  const u16* Mb = Mbuf + (size_t)b * 1152 * HW + (size_t)128 * HW;
  const int t = threadIdx.x;
  const int lane = t & 63, w = t >> 6;
  const int wr = w >> 1, wc = w & 1;
  const int m = lane & 15, quad = lane >> 4;
  f32x4 acc[4][4];
  #pragma unroll
  for (int i = 0; i < 4; i++)
    #pragma unroll
    for (int j = 0; j < 4; j++) acc[i][j] = (f32x4){0.f, 0.f, 0.f, 0.f};

  for (int k0c = 0; k0c < 1024; k0c += 64) {
    for (int e = t; e < 1024; e += 256) {
      int r = e >> 3, kc8 = (e & 7) * 8;
      *(uint4*)&As[r][kc8] = *(const uint4*)&Ab[(size_t)(row0 + r) * 1024 + k0c + kc8];
    }
    for (int e = t; e < 1024; e += 256) {
      int kc = e >> 4, c8 = (e & 15) * 8;
      uint4 v = *(const uint4*)&Mb[(size_t)(k0c + kc) * HW + col0 + c8];
      u16 tmp[8]; *(uint4*)tmp = v;
      #pragma unroll
      for (int uu = 0; uu < 8; uu++) {
        int u = (uu + lane) & 7;
        Bs[c8 + u][kc] = tmp[u];
      }
    }
    __syncthreads();
    #pragma unroll
    for (int k0 = 0; k0 < 64; k0 += 32) {
      short8 af[4], bf[4];
      #pragma unroll
      for (int i = 0; i < 4; i++) af[i] = *(const short8*)&As[wr * 64 + i * 16 + m][k0 + quad * 8];
      #pragma unroll
      for (int j = 0; j < 4; j++) bf[j] = *(const short8*)&Bs[wc * 64 + j * 16 + m][k0 + quad * 8];
      #pragma unroll
      for (int i = 0; i < 4; i++)
        #pragma unroll
        for (int j = 0; j < 4; j++)
          acc[i][j] = __builtin_amdgcn_mfma_f32_16x16x32_bf16(af[i], bf[j], acc[i][j], 0, 0, 0);
    }
    __syncthreads();
  }
  #pragma unroll
  for (int i = 0; i < 4; i++)
    #pragma unroll
    for (int j = 0; j < 4; j++) {
      int col = col0 + wc * 64 + j * 16 + m;
      #pragma unroll
      for (int r = 0; r < 4; r++) {
        int row = row0 + wr * 64 + i * 16 + quad * 4 + r;
        ybuf[((size_t)b * 256 + row) * HW + col] = f2b(acc[i][j][r]);
      }
    }
}

// ---------------------------------------------------------------- BatchNorm
__global__ __launch_bounds__(256) void bn_stats(
    const u16* __restrict__ y, float* __restrict__ st) {
  const int o = blockIdx.x;
  const int t = threadIdx.x;
  float sum = 0.f, ss = 0.f;
  for (int bb = 0; bb < 2; bb++) {
    const u16* p = y + ((size_t)bb * 256 + o) * HW;
    for (int e = t; e < HW / 8; e += 256) {
      uint4 v = ((const uint4*)p)[e];
      float f[8];
      unpack8(v, f);
      #pragma unroll
      for (int k = 0; k < 8; k++) { sum += f[k]; ss += f[k] * f[k]; }
    }
  }
  __shared__ float red[8];
  sum = wave_sum(sum); ss = wave_sum(ss);
  if ((t & 63) == 0) { red[t >> 6] = sum; red[4 + (t >> 6)] = ss; }
  __syncthreads();
  if (t == 0) {
    float mean = (red[0] + red[1] + red[2] + red[3]) / 32768.f;
    float var = (red[4] + red[5] + red[6] + red[7]) / 32768.f - mean * mean;
    st[o * 2] = mean;
    st[o * 2 + 1] = rsqrtf(var + 1e-5f);
  }
}

__global__ __launch_bounds__(256) void bn_apply(
    const u16* __restrict__ y, const float* __restrict__ st,
    const u16* __restrict__ gamma, const u16* __restrict__ beta,
    const int* __restrict__ flag, void* __restrict__ out) {
  const int idx8 = blockIdx.x * 256 + threadIdx.x;
  const int r = idx8 >> 11;
  const int o = r & 255;
  float mean = st[o * 2], istd = st[o * 2 + 1];
  float g = b2f(gamma[o]), be = b2f(beta[o]);
  uint4 v = ((const uint4*)y)[idx8];
  float f[8];
  unpack8(v, f);
  float rr[8];
  #pragma unroll
  for (int k = 0; k < 8; k++) rr[k] = fmaxf((f[k] - mean) * istd * g + be, 0.f);
  if (*flag) {
    float* of = (float*)out + (size_t)idx8 * 8;
    *(float4*)of = make_float4(rr[0], rr[1], rr[2], rr[3]);
    *(float4*)(of + 4) = make_float4(rr[4], rr[5], rr[6], rr[7]);
  } else {
    u32 p0 = (u32)f2b(rr[0]) | ((u32)f2b(rr[1]) << 16);
    u32 p1 = (u32)f2b(rr[2]) | ((u32)f2b(rr[3]) << 16);
    u32 p2 = (u32)f2b(rr[4]) | ((u32)f2b(rr[5]) << 16);
    u32 p3 = (u32)f2b(rr[6]) | ((u32)f2b(rr[7]) << 16);
    ((uint4*)out)[idx8] = make_uint4(p0, p1, p2, p3);
  }
}

// ----------------------------------------------------------------------------
extern "C" void kernel_launch(void* const* d_in, const int* in_sizes, int n_in,
                              void* d_out, int out_size, void* d_ws, size_t ws_size,
                              hipStream_t stream) {
  float* G     = (float*)d_ws;           // 819,200 f32 (2 x G_SZ)
  float* score = G + 819200;             // 262,144
  float* invQ  = score + 262144;         // 512
  float* invK  = invQ + 512;             // 4,096
  float* W2    = invK + 4096;            // 524,288
  float* Wfin  = W2 + 524288;            // slot reused: u16 Wfin16
  float* bnst  = Wfin + 524288;          // 512
  int* flag    = (int*)(bnst + 512);     // 16
  u16* Sbuf    = (u16*)(flag + 16);      // S_TOTAL u16
  u16* Mbuf    = Sbuf + S_TOTAL;         // 37,748,736 u16
  u16* ybuf    = Mbuf + 37748736;        // 8,388,608 u16
  u16* Wfin16  = (u16*)Wfin;
  float* lgbuf = (float*)ybuf;           // alias: consumed before y_gemm writes ybuf

  probe<<<1, 64, 0, stream>>>((const u32*)d_in[10], flag);
  convert_all<<<dim3(1024, 1, 12), 256, 0, stream>>>(
      d_in[0], d_in[1], d_in[2], d_in[3], d_in[4], d_in[5], d_in[6], d_in[7],
      d_in[8], d_in[9], d_in[10], d_in[11], Sbuf, flag);

  sur_w<<<dim3(64, 2, 4), 256, 0, stream>>>(
      Sbuf + S_CEN, Sbuf + S_W1, Sbuf + S_B1, Sbuf + S_W2, Sbuf + S_B2,
      Sbuf + S_SW, lgbuf);
  sur_scatter<<<dim3(32, 4, 8), 256, 0, stream>>>(
      Sbuf + S_CEN, lgbuf, Sbuf + S_SW, Mbuf);
  hipMemsetAsync(G, 0, 819200 * sizeof(float), stream);
  gram_mfma<<<672, 256, 0, stream>>>(Mbuf, G);
  mirror_S<<<8, 256, 0, stream>>>(G);
  qnorm<<<8, 64, 0, stream>>>(Sbuf + S_QW, G, invQ);
  knorm<<<dim3(512, 4, 2), 256, 0, stream>>>(Sbuf + S_KW, G, invK);
  score2<<<dim3(8, 4, 2), 256, 0, stream>>>(Sbuf + S_QW, Sbuf + S_KW, G, score);
  in_softmax<<<8, 256, 0, stream>>>(score, invQ, invK);
  attnW2<<<dim3(4, 8, 2), 256, 0, stream>>>(score, Sbuf + S_VW, W2);
  wfin_k<<<dim3(1024, 2), 256, 0, stream>>>(Sbuf + S_OW, W2, Wfin16);
  y_gemm_mfma<<<dim3(128, 2, 2), 256, 0, stream>>>(Wfin16, Mbuf, ybuf);
  bn_stats<<<256, 256, 0, stream>>>(ybuf, bnst);
  bn_apply<<<4096, 256, 0, stream>>>(ybuf, bnst, Sbuf + S_GAMMA, Sbuf + S_BETA,
                                     flag, d_out);
}

// Round 9
// 528.667 us; speedup vs baseline: 1.2091x; 1.0508x over previous
//
#include <hip/hip_runtime.h>

// Gram-trick + MFMA. Ladder: 2310 -> 1380 -> 626 -> 639 -> 595 -> 555.
// R9: sur_w co-split (1024 blocks, 3 blk/CU; was 512 blk / 2 per CU, VALUBusy 25%);
// attnW2 j-to-grid (256 blocks, coalesced vw reads).

#define HW 16384
typedef unsigned short u16;
typedef unsigned int u32;
typedef __attribute__((ext_vector_type(8))) short short8;
typedef __attribute__((ext_vector_type(4))) float f32x4;

// staging offsets (u16 elements)
#define S_CEN 0
#define S_QW 1048576
#define S_KW 1056768
#define S_VW 1581056
#define S_W1 2105344
#define S_B1 2142208
#define S_W2 2142336
#define S_B2 2143360
#define S_SW 2143392
#define S_OW 2143400
#define S_GAMMA 2208936
#define S_BETA 2209192
#define S_TOTAL 2209456

// compact Gram layout per batch (f32 elements)
#define G_D1 0       // 128x128, stride 128
#define G_D2 16384   // 128x1024, stride 1024
#define G_S 147456   // 4 blocks of 256x256, stride 256
#define G_SZ 409600

__device__ __forceinline__ float b2f(u16 u) { return __uint_as_float(((u32)u) << 16); }
__device__ __forceinline__ u16 f2b(float f) {
  u32 u = __float_as_uint(f);
  return (u16)((u + 0x7FFFu + ((u >> 16) & 1u)) >> 16);  // RNE
}
__device__ __forceinline__ float wave_sum(float v) {
  #pragma unroll
  for (int off = 32; off > 0; off >>= 1) v += __shfl_xor(v, off, 64);
  return v;
}
__device__ __forceinline__ float wave_max(float v) {
  #pragma unroll
  for (int off = 32; off > 0; off >>= 1) v = fmaxf(v, __shfl_xor(v, off, 64));
  return v;
}
__device__ __forceinline__ void unpack8(uint4 v, float* f) {
  f[0] = __uint_as_float(v.x << 16); f[1] = __uint_as_float(v.x & 0xFFFF0000u);
  f[2] = __uint_as_float(v.y << 16); f[3] = __uint_as_float(v.y & 0xFFFF0000u);
  f[4] = __uint_as_float(v.z << 16); f[5] = __uint_as_float(v.z & 0xFFFF0000u);
  f[6] = __uint_as_float(v.w << 16); f[7] = __uint_as_float(v.w & 0xFFFF0000u);
}

// ------------------------------------------------------------ dtype probe
__global__ void probe(const u32* __restrict__ g, int* __restrict__ flag) {
  if (threadIdx.x == 0) {
    int ok = 1;
    #pragma unroll
    for (int i = 0; i < 4; i++) {
      u32 w = g[i];
      u32 lo = w & 0xFFFFu, hi = w >> 16;
      ok &= (lo >= 0x3E00u && lo <= 0x4100u) ? 1 : 0;
      ok &= (hi >= 0x3E00u && hi <= 0x4100u) ? 1 : 0;
    }
    *flag = ok ? 0 : 1;  // 0 = bf16 inputs, 1 = f32 inputs
  }
}

// ------------------------------------------------------------ stage inputs -> bf16
__global__ __launch_bounds__(256) void convert_all(
    const void* p0, const void* p1, const void* p2, const void* p3,
    const void* p4, const void* p5, const void* p6, const void* p7,
    const void* p8, const void* p9, const void* p10, const void* p11,
    u16* __restrict__ S, const int* __restrict__ flag) {
  const void* src; int n; int off;
  switch (blockIdx.z) {
    case 0:  src = p0;  n = 1048576; off = S_CEN; break;
    case 1:  src = p1;  n = 8192;    off = S_QW; break;
    case 2:  src = p2;  n = 524288;  off = S_KW; break;
    case 3:  src = p3;  n = 524288;  off = S_VW; break;
    case 4:  src = p4;  n = 36864;   off = S_W1; break;
    case 5:  src = p5;  n = 128;     off = S_B1; break;
    case 6:  src = p6;  n = 1024;    off = S_W2; break;
    case 7:  src = p7;  n = 32;      off = S_B2; break;
    case 8:  src = p8;  n = 8;       off = S_SW; break;
    case 9:  src = p9;  n = 65536;   off = S_OW; break;
    case 10: src = p10; n = 256;     off = S_GAMMA; break;
    default: src = p11; n = 256;     off = S_BETA; break;
  }
  int idx = (blockIdx.x * 256 + threadIdx.x) * 4;
  if (idx >= n) return;
  u16* dst = S + off + idx;
  if (*flag) {
    float4 v = ((const float4*)src)[idx >> 2];
    dst[0] = f2b(v.x); dst[1] = f2b(v.y); dst[2] = f2b(v.z); dst[3] = f2b(v.w);
  } else {
    *(ushort4*)dst = ((const ushort4*)src)[idx >> 2];
  }
}

// --- sur_w v3: 128 px x 2 co-halves per block; conv + softmax -> lgbuf[b][si][s][8]
__global__ __launch_bounds__(256) void sur_w(
    const u16* __restrict__ cen, const u16* __restrict__ w1g,
    const u16* __restrict__ b1g, const u16* __restrict__ w2g,
    const u16* __restrict__ b2g, const u16* __restrict__ swg,
    float* __restrict__ lgbuf) {
  const int si = blockIdx.z;
  const int d = 1 << si;
  __shared__ float w1s[9216];  // [tap][ci][co]
  __shared__ float w2s[256];
  __shared__ float b1s[32];
  __shared__ float b2s[8];
  __shared__ float part[2][128][8];
  const int t = threadIdx.x;
  for (int e = t; e < 9216; e += 256) {
    int tap = e >> 10, rem = e & 1023, ci = rem >> 5, co = rem & 31;
    w1s[e] = b2f(w1g[si * 9216 + co * 288 + ci * 9 + tap]);
  }
  w2s[t] = b2f(w2g[si * 256 + t]);
  if (t < 32) b1s[t] = b2f(b1g[si * 32 + t]);
  if (t < 8) b2s[t] = b2f(b2g[si * 8 + t]);
  __syncthreads();

  const int b = blockIdx.y;
  const int h = blockIdx.x;          // image row
  const int px = t & 127, half = t >> 7;
  const int w = px, co0 = half * 16;

  float s0 = b2f(swg[si * 2 + 0]), s1 = b2f(swg[si * 2 + 1]);
  float mx = fmaxf(s0, s1);
  float e0 = expf(s0 - mx), e1 = expf(s1 - mx);
  float w20 = e0 / (e0 + e1);

  const u16* cb = cen + (size_t)b * 32 * HW;

  float h1[16];
  #pragma unroll
  for (int i = 0; i < 16; i++) h1[i] = 0.f;
  for (int tap = 0; tap < 9; tap++) {
    int ky = tap / 3, kx = tap - ky * 3;
    int y = h + (ky - 1) * d, x = w + (kx - 1) * d;
    if (y < 0 || y >= 128 || x < 0 || x >= 128) continue;
    int off = y * 128 + x;
    const float* wt = &w1s[tap * 1024 + co0];
    for (int ci = 0; ci < 32; ci++) {
      float v = b2f(cb[(size_t)ci * HW + off]);
      #pragma unroll
      for (int i = 0; i < 16; i++) h1[i] = fmaf(v, wt[ci * 32 + i], h1[i]);
    }
  }
  #pragma unroll
  for (int i = 0; i < 16; i++) h1[i] = fmaxf(h1[i] + b1s[co0 + i], 0.f);

  float lp[8];
  #pragma unroll
  for (int k = 0; k < 8; k++) lp[k] = half ? 0.f : b2s[k];
  #pragma unroll
  for (int i = 0; i < 16; i++) {
    float v = h1[i];
    #pragma unroll
    for (int k = 0; k < 8; k++) lp[k] = fmaf(v, w2s[k * 32 + co0 + i], lp[k]);
  }
  #pragma unroll
  for (int k = 0; k < 8; k++) part[half][px][k] = lp[k];
  __syncthreads();
  if (t < 128) {
    float lg[8];
    #pragma unroll
    for (int k = 0; k < 8; k++) lg[k] = part[0][t][k] + part[1][t][k];
    float lm = lg[0];
    #pragma unroll
    for (int k = 1; k < 8; k++) lm = fmaxf(lm, lg[k]);
    float ls = 0.f;
    #pragma unroll
    for (int k = 0; k < 8; k++) { lg[k] = expf(lg[k] - lm); ls += lg[k]; }
    float inv = w20 / ls;
    float* lp2 = lgbuf + ((size_t)(b * 4 + si) * HW + h * 128 + t) * 8;
    *(float4*)lp2 = make_float4(lg[0] * inv, lg[1] * inv, lg[2] * inv, lg[3] * inv);
    *(float4*)(lp2 + 4) = make_float4(lg[4] * inv, lg[5] * inv, lg[6] * inv, lg[7] * inv);
  }
}

// ------------- sur_scatter: neighbors + sumx/cenx/sur writes (2px, 8ch per thread)
__global__ __launch_bounds__(256) void sur_scatter(
    const u16* __restrict__ cen, const float* __restrict__ lgbuf,
    const u16* __restrict__ swg, u16* __restrict__ Mbuf) {
  const int z = blockIdx.z;
  const int b = z >> 2, si = z & 3, d = 1 << si;
  const int c0 = blockIdx.y * 8;
  const int t = threadIdx.x;
  const int s = (blockIdx.x * 256 + t) * 2;  // even
  const int h = s >> 7, w = s & 127;

  float s0 = b2f(swg[si * 2 + 0]), s1 = b2f(swg[si * 2 + 1]);
  float mx = fmaxf(s0, s1);
  float e0 = expf(s0 - mx), e1 = expf(s1 - mx);
  float w20 = e0 / (e0 + e1), w21 = e1 / (e0 + e1);

  const float* lpa = lgbuf + ((size_t)(b * 4 + si) * HW + s) * 8;
  float4 la0 = *(const float4*)lpa, la1 = *(const float4*)(lpa + 4);
  float4 lb0 = *(const float4*)(lpa + 8), lb1 = *(const float4*)(lpa + 12);
  float lga[8] = {la0.x, la0.y, la0.z, la0.w, la1.x, la1.y, la1.z, la1.w};
  float lgb[8] = {lb0.x, lb0.y, lb0.z, lb0.w, lb1.x, lb1.y, lb1.z, lb1.w};

  const int dy[8] = {-d, -d, -d, 0, 0, d, d, d};
  const int dx[8] = {-d, 0, d, -d, d, -d, 0, d};
  int offa[8], offb[8];
  #pragma unroll
  for (int k = 0; k < 8; k++) {
    int y = h + dy[k]; y = y < 0 ? -y : (y > 127 ? 254 - y : y);
    int xa = w + dx[k]; xa = xa < 0 ? -xa : (xa > 127 ? 254 - xa : xa);
    int xb = w + 1 + dx[k]; xb = xb < 0 ? -xb : (xb > 127 ? 254 - xb : xb);
    offa[k] = y * 128 + xa;
    offb[k] = y * 128 + xb;
  }
  const u16* cb = cen + (size_t)b * 32 * HW;
  u16* Mb = Mbuf + (size_t)b * 1152 * HW;
  for (int c = c0; c < c0 + 8; c++) {
    const u16* cc = cb + (size_t)c * HW;
    u32 cvp = *(const u32*)&cc[s];
    float cva = __uint_as_float(cvp << 16), cvb = __uint_as_float(cvp & 0xFFFF0000u);
    float nba[8], nbb[8];
    #pragma unroll
    for (int k = 0; k < 8; k++) { nba[k] = b2f(cc[offa[k]]); nbb[k] = b2f(cc[offb[k]]); }
    float sxa = 0.f, mna = 0.f, sxb = 0.f, mnb = 0.f;
    #pragma unroll
    for (int k = 0; k < 8; k++) {
      sxa = fmaf(lga[k], nba[k], sxa); mna += nba[k];
      sxb = fmaf(lgb[k], nbb[k], sxb); mnb += nbb[k];
    }
    float suma = sxa + cva * w21, sumb = sxb + cvb * w21;
    u32 cx = (u32)f2b(mna * 0.125f * w20 + cva * w21) |
             ((u32)f2b(mnb * 0.125f * w20 + cvb * w21) << 16);
    *(u32*)&Mb[(size_t)(32 * si + c) * HW + s] = cx;
    #pragma unroll
    for (int k = 0; k < 8; k++) {
      u32 pk = (u32)f2b(nba[k] - suma) | ((u32)f2b(nbb[k] - sumb) << 16);
      *(u32*)&Mb[(size_t)(128 + 256 * si + k * 32 + c) * HW + s] = pk;
    }
  }
}

// ------------ Gram via MFMA: BK=64 (4 blk/CU), 21 tiles, XCD-combo swizzle, atomics
__global__ __launch_bounds__(256) void gram_mfma(
    const u16* __restrict__ Mbuf, float* __restrict__ G) {
  const int id = blockIdx.x;
  const int tile = id >> 5, combo = id & 31;
  const int ks = combo >> 1, b = combo & 1;
  int r0, c0, gstride; size_t goff;
  if (tile == 0) { r0 = 0; c0 = 0; goff = G_D1; gstride = 128; }
  else if (tile < 9) { r0 = 0; c0 = 128 * tile; goff = G_D2 + (size_t)(tile - 1) * 128; gstride = 1024; }
  else if (tile < 17) {
    int t2 = tile - 9; int j = t2 >> 1, p = t2 & 1;
    r0 = 128 + 256 * j + 128 * p; c0 = r0;
    goff = G_S + (size_t)j * 65536 + (size_t)p * (128 * 256 + 128); gstride = 256;
  } else {
    int j = tile - 17;
    r0 = 128 + 256 * j; c0 = r0 + 128;
    goff = G_S + (size_t)j * 65536 + 128; gstride = 256;
  }
  const u16* Mb = Mbuf + (size_t)b * 1152 * HW;
  __shared__ u16 As[128][72];
  __shared__ u16 Bs[128][72];
  const int t = threadIdx.x;
  const int lane = t & 63, w = t >> 6;
  const int wr = w >> 1, wc = w & 1;
  const int m = lane & 15, quad = lane >> 4;
  f32x4 acc[4][4];
  #pragma unroll
  for (int i = 0; i < 4; i++)
    #pragma unroll
    for (int j = 0; j < 4; j++) acc[i][j] = (f32x4){0.f, 0.f, 0.f, 0.f};

  for (int s0 = ks * 1024; s0 < ks * 1024 + 1024; s0 += 64) {
    for (int e = t; e < 1024; e += 256) {
      int r = e >> 3, c8 = (e & 7) * 8;
      *(uint4*)&As[r][c8] = *(const uint4*)&Mb[(size_t)(r0 + r) * HW + s0 + c8];
      *(uint4*)&Bs[r][c8] = *(const uint4*)&Mb[(size_t)(c0 + r) * HW + s0 + c8];
    }
    __syncthreads();
    #pragma unroll
    for (int k0 = 0; k0 < 64; k0 += 32) {
      short8 af[4], bf[4];
      #pragma unroll
      for (int i = 0; i < 4; i++) af[i] = *(const short8*)&As[wr * 64 + i * 16 + m][k0 + quad * 8];
      #pragma unroll
      for (int j = 0; j < 4; j++) bf[j] = *(const short8*)&Bs[wc * 64 + j * 16 + m][k0 + quad * 8];
      #pragma unroll
      for (int i = 0; i < 4; i++)
        #pragma unroll
        for (int j = 0; j < 4; j++)
          acc[i][j] = __builtin_amdgcn_mfma_f32_16x16x32_bf16(af[i], bf[j], acc[i][j], 0, 0, 0);
    }
    __syncthreads();
  }
  float* Gb = G + (size_t)b * G_SZ + goff;
  #pragma unroll
  for (int i = 0; i < 4; i++)
    #pragma unroll
    for (int j = 0; j < 4; j++) {
      int col = wc * 64 + j * 16 + m;
      #pragma unroll
      for (int r = 0; r < 4; r++) {
        int row = wr * 64 + i * 16 + quad * 4 + r;
        atomicAdd(&Gb[(size_t)row * gstride + col], acc[i][j][r]);
      }
    }
}

// ------------------------------------- mirror S_j lower-left = upper-right^T
__global__ __launch_bounds__(256) void mirror_S(float* __restrict__ G) {
  const int j = blockIdx.x & 3, b = blockIdx.x >> 2;
  float* base = G + (size_t)b * G_SZ + G_S + (size_t)j * 65536;
  const int t = threadIdx.x;
  for (int e = t; e < 16384; e += 256) {
    int rr = e >> 7, cc = e & 127;
    base[(size_t)(128 + rr) * 256 + cc] = base[(size_t)cc * 256 + 128 + rr];
  }
}

// ------------------------------------------------------------------ Q row inv-norms
__global__ __launch_bounds__(64) void qnorm(
    const u16* __restrict__ qw, const float* __restrict__ G,
    float* __restrict__ invQ) {
  const int bn = blockIdx.x, b = bn >> 2, n = bn & 3;
  const int rq = threadIdx.x;
  const int i = rq & 3, q1r = rq >> 2;
  const u16* qr = qw + ((size_t)(i * 64) + 16 * n + q1r) * 32;
  float v[32];
  #pragma unroll
  for (int c = 0; c < 32; c++) v[c] = b2f(qr[c]);
  const float* D1 = G + (size_t)b * G_SZ;
  float ss = 0.f;
  for (int c = 0; c < 32; c++) {
    float tmp = 0.f;
    #pragma unroll
    for (int c2 = 0; c2 < 32; c2++) tmp = fmaf(v[c2], D1[(size_t)(32 * i + c2) * 128 + 32 * i + c], tmp);
    ss = fmaf(tmp, v[c], ss);
  }
  invQ[bn * 64 + rq] = 1.f / fmaxf(sqrtf(fmaxf(ss, 0.f)), 1e-12f);
}

// ------------------------------------------------------------------ K row inv-norms
__global__ __launch_bounds__(256) void knorm(
    const u16* __restrict__ kw, const float* __restrict__ G,
    float* __restrict__ invK) {
  const int rk = blockIdx.x, n = blockIdx.y, b = blockIdx.z;
  const int j = rk & 3, kk = rk >> 2;
  const u16* kr = kw + ((size_t)(j * 512) + 128 * n + kk) * 256;
  __shared__ float vs[256];
  const int t = threadIdx.x;
  vs[t] = b2f(kr[t]);
  __syncthreads();
  const float* S = G + (size_t)b * G_SZ + G_S + (size_t)j * 65536;
  float tmp = 0.f;
  for (int c2 = 0; c2 < 256; c2++) tmp = fmaf(vs[c2], S[(size_t)c2 * 256 + t], tmp);
  tmp *= vs[t];
  tmp = wave_sum(tmp);
  __shared__ float red[4];
  if ((t & 63) == 0) red[t >> 6] = tmp;
  __syncthreads();
  if (t == 0) {
    float tot = fmaxf(red[0] + red[1] + red[2] + red[3], 0.f);
    invK[(size_t)(b * 4 + n) * 512 + rk] = 1.f / fmaxf(sqrtf(tot), 1e-12f);
  }
}

// ---------- score2 (kk-split x2): per (j,half,n,b): KD = D2_j . kw_half^T, then q_w.KD
__global__ __launch_bounds__(256) void score2(
    const u16* __restrict__ qw, const u16* __restrict__ kw,
    const float* __restrict__ G, float* __restrict__ score) {
  const int jj = blockIdx.x;        // 0..7
  const int j = jj >> 1, half = jj & 1;
  const int n = blockIdx.y, b = blockIdx.z;
  const float* D2 = G + (size_t)b * G_SZ + G_D2;
  const u16* kwb = kw + ((size_t)(j * 512) + 128 * n + half * 64) * 256;  // 64 rows
  __shared__ float As[64][132];
  __shared__ u16 Bs[64][68];
  __shared__ float KD[128][68];
  __shared__ float qws[64][32];
  const int t = threadIdx.x;
  const int tx = t & 7, ty = t >> 3;
  float acc[4][8];
  #pragma unroll
  for (int i = 0; i < 4; i++)
    #pragma unroll
    for (int u = 0; u < 8; u++) acc[i][u] = 0.f;
  for (int ch0 = 0; ch0 < 256; ch0 += 64) {
    for (int e = t; e < 8192; e += 256) {
      int r = e >> 6, kc = e & 63;
      As[kc][r] = D2[(size_t)r * 1024 + j * 256 + ch0 + kc];
    }
    for (int e = t; e < 4096; e += 256) {
      int r = e >> 6, kc = e & 63;
      Bs[kc][r] = kwb[(size_t)r * 256 + ch0 + kc];
    }
    __syncthreads();
    #pragma unroll 4
    for (int kc = 0; kc < 64; kc++) {
      float a[4];
      #pragma unroll
      for (int i = 0; i < 4; i++) a[i] = As[kc][ty * 4 + i];
      float bb[8];
      #pragma unroll
      for (int u = 0; u < 8; u++) bb[u] = b2f(Bs[kc][tx * 8 + u]);
      #pragma unroll
      for (int i = 0; i < 4; i++)
        #pragma unroll
        for (int u = 0; u < 8; u++) acc[i][u] = fmaf(a[i], bb[u], acc[i][u]);
    }
    __syncthreads();
  }
  #pragma unroll
  for (int i = 0; i < 4; i++)
    #pragma unroll
    for (int u = 0; u < 8; u++) KD[ty * 4 + i][tx * 8 + u] = acc[i][u];
  for (int e = t; e < 2048; e += 256) {
    int q = e >> 5, c = e & 31;
    int i = q & 3, q1r = q >> 2;
    qws[q][c] = b2f(qw[((size_t)(i * 64) + 16 * n + q1r) * 32 + c]);
  }
  __syncthreads();
  float* sb = score + (size_t)(b * 4 + n) * 64 * 512;
  for (int e = t; e < 4096; e += 256) {
    int q = e >> 6, kkl = e & 63;
    int i = q & 3;
    float s = 0.f;
    #pragma unroll
    for (int c = 0; c < 32; c++) s = fmaf(qws[q][c], KD[i * 32 + c][kkl], s);
    sb[(size_t)q * 512 + 4 * (half * 64 + kkl) + j] = s;
  }
}

// ------------------------------------------ scale + InstanceNorm + row softmax
__global__ __launch_bounds__(256) void in_softmax(
    float* __restrict__ score, const float* __restrict__ invQ,
    const float* __restrict__ invK) {
  const int bn = blockIdx.x;
  float* sb = score + (size_t)bn * 64 * 512;
  const float* iQ = invQ + bn * 64;
  const float* iK = invK + bn * 512;
  const int t = threadIdx.x;
  float sum = 0.f, ss = 0.f;
  const float isc = 1.f / 128.f;
  for (int e = t; e < 32768; e += 256) {
    int q = e >> 9, kk = e & 511;
    float v = sb[e] * iQ[q] * iK[kk] * isc;
    sb[e] = v;
    sum += v; ss += v * v;
  }
  __shared__ float red[8];
  sum = wave_sum(sum); ss = wave_sum(ss);
  if ((t & 63) == 0) { red[t >> 6] = sum; red[4 + (t >> 6)] = ss; }
  __syncthreads();
  float mean = (red[0] + red[1] + red[2] + red[3]) * (1.f / 32768.f);
  float var = (red[4] + red[5] + red[6] + red[7]) * (1.f / 32768.f) - mean * mean;
  float istd = rsqrtf(var + 1e-5f);
  const int wv = t >> 6, lane = t & 63;
  for (int r = wv; r < 64; r += 4) {
    float z[8];
    float m = -1e30f;
    #pragma unroll
    for (int j = 0; j < 8; j++) {
      z[j] = (sb[(size_t)r * 512 + lane + 64 * j] - mean) * istd;
      m = fmaxf(m, z[j]);
    }
    m = wave_max(m);
    float sloc = 0.f;
    #pragma unroll
    for (int j = 0; j < 8; j++) { z[j] = expf(z[j] - m); sloc += z[j]; }
    sloc = wave_sum(sloc);
    float rinv = 1.f / sloc;
    #pragma unroll
    for (int j = 0; j < 8; j++) sb[(size_t)r * 512 + lane + 64 * j] = z[j] * rinv;
  }
}

// --------- attnW2 v2: grid (j*4+n, q0, b); thread = out channel; coalesced vw reads
__global__ __launch_bounds__(256) void attnW2(
    const float* __restrict__ attn, const u16* __restrict__ vw,
    float* __restrict__ W2) {
  const int j = blockIdx.x >> 2, n = blockIdx.x & 3;
  const int q0 = blockIdx.y * 8, b = blockIdx.z, bn = b * 4 + n;
  const float* ab = attn + (size_t)bn * 64 * 512;
  const int t = threadIdx.x;  // = ch 0..255
  __shared__ float at_s[8][128];
  for (int e = t; e < 1024; e += 256) {
    int qg = e >> 7, kk = e & 127;
    at_s[qg][kk] = ab[(size_t)(q0 + qg) * 512 + 4 * kk + j];
  }
  __syncthreads();
  float acc[8];
  #pragma unroll
  for (int qg = 0; qg < 8; qg++) acc[qg] = 0.f;
  const u16* vcol = vw + ((size_t)(j * 512) + 128 * n) * 256 + t;
  for (int kk = 0; kk < 128; kk++) {
    float v = b2f(vcol[(size_t)kk * 256]);
    #pragma unroll
    for (int qg = 0; qg < 8; qg++) acc[qg] = fmaf(at_s[qg][kk], v, acc[qg]);
  }
  #pragma unroll
  for (int qg = 0; qg < 8; qg++)
    W2[((size_t)bn * 64 + q0 + qg) * 1024 + j * 256 + t] = acc[qg];
}

// ------------------------------------------ Wfin16[b][o][jc] = bf16(out_w . W2)
__global__ __launch_bounds__(256) void wfin_k(
    const u16* __restrict__ ow, const float* __restrict__ W2,
    u16* __restrict__ Wfin16) {
  const int jc = blockIdx.x, b = blockIdx.y;
  __shared__ float col[256];
  const int t = threadIdx.x;
  col[t] = W2[((size_t)b * 256 + t) * 1024 + jc];
  __syncthreads();
  float acc = 0.f;
  const u16* owr = ow + (size_t)t * 256;
  for (int c = 0; c < 256; c++) acc = fmaf(b2f(owr[c]), col[c], acc);
  Wfin16[((size_t)b * 256 + t) * 1024 + jc] = f2b(acc);
}

// -------------------------------------- y = Wfin(bf16) @ sur via MFMA (bf16 out)
__global__ __launch_bounds__(256) void y_gemm_mfma(
    const u16* __restrict__ Wfin16, const u16* __restrict__ Mbuf,
    u16* __restrict__ ybuf) {
  const int b = blockIdx.z, row0 = blockIdx.y * 128, col0 = blockIdx.x * 128;
  __shared__ u16 As[128][72];
  __shared__ u16 Bs[128][72];
  const u16* Ab = Wfin16 + (size_t)b * 256 * 1024;
  const u16* Mb = Mbuf + (size_t)b * 1152 * HW + (size_t)128 * HW;
  const int t = threadIdx.x;
  const int lane = t & 63, w = t >> 6;
  const int wr = w >> 1, wc = w & 1;
  const int m = lane & 15, quad = lane >> 4;
  f32x4 acc[4][4];
  #pragma unroll
  for (int i = 0; i < 4; i++)
    #pragma unroll
    for (int j = 0; j < 4; j++) acc[i][j] = (f32x4){0.f, 0.f, 0.f, 0.f};

  for (int k0c = 0; k0c < 1024; k0c += 64) {
    for (int e = t; e < 1024; e += 256) {
      int r = e >> 3, kc8 = (e & 7) * 8;
      *(uint4*)&As[r][kc8] = *(const uint4*)&Ab[(size_t)(row0 + r) * 1024 + k0c + kc8];
    }
    for (int e = t; e < 1024; e += 256) {
      int kc = e >> 4, c8 = (e & 15) * 8;
      uint4 v = *(const uint4*)&Mb[(size_t)(k0c + kc) * HW + col0 + c8];
      u16 tmp[8]; *(uint4*)tmp = v;
      #pragma unroll
      for (int uu = 0; uu < 8; uu++) {
        int u = (uu + lane) & 7;
        Bs[c8 + u][kc] = tmp[u];
      }
    }
    __syncthreads();
    #pragma unroll
    for (int k0 = 0; k0 < 64; k0 += 32) {
      short8 af[4], bf[4];
      #pragma unroll
      for (int i = 0; i < 4; i++) af[i] = *(const short8*)&As[wr * 64 + i * 16 + m][k0 + quad * 8];
      #pragma unroll
      for (int j = 0; j < 4; j++) bf[j] = *(const short8*)&Bs[wc * 64 + j * 16 + m][k0 + quad * 8];
      #pragma unroll
      for (int i = 0; i < 4; i++)
        #pragma unroll
        for (int j = 0; j < 4; j++)
          acc[i][j] = __builtin_amdgcn_mfma_f32_16x16x32_bf16(af[i], bf[j], acc[i][j], 0, 0, 0);
    }
    __syncthreads();
  }
  #pragma unroll
  for (int i = 0; i < 4; i++)
    #pragma unroll
    for (int j = 0; j < 4; j++) {
      int col = col0 + wc * 64 + j * 16 + m;
      #pragma unroll
      for (int r = 0; r < 4; r++) {
        int row = row0 + wr * 64 + i * 16 + quad * 4 + r;
        ybuf[((size_t)b * 256 + row) * HW + col] = f2b(acc[i][j][r]);
      }
    }
}

// ---------------------------------------------------------------- BatchNorm
__global__ __launch_bounds__(256) void bn_stats(
    const u16* __restrict__ y, float* __restrict__ st) {
  const int o = blockIdx.x;
  const int t = threadIdx.x;
  float sum = 0.f, ss = 0.f;
  for (int bb = 0; bb < 2; bb++) {
    const u16* p = y + ((size_t)bb * 256 + o) * HW;
    for (int e = t; e < HW / 8; e += 256) {
      uint4 v = ((const uint4*)p)[e];
      float f[8];
      unpack8(v, f);
      #pragma unroll
      for (int k = 0; k < 8; k++) { sum += f[k]; ss += f[k] * f[k]; }
    }
  }
  __shared__ float red[8];
  sum = wave_sum(sum); ss = wave_sum(ss);
  if ((t & 63) == 0) { red[t >> 6] = sum; red[4 + (t >> 6)] = ss; }
  __syncthreads();
  if (t == 0) {
    float mean = (red[0] + red[1] + red[2] + red[3]) / 32768.f;
    float var = (red[4] + red[5] + red[6] + red[7]) / 32768.f - mean * mean;
    st[o * 2] = mean;
    st[o * 2 + 1] = rsqrtf(var + 1e-5f);
  }
}

__global__ __launch_bounds__(256) void bn_apply(
    const u16* __restrict__ y, const float* __restrict__ st,
    const u16* __restrict__ gamma, const u16* __restrict__ beta,
    const int* __restrict__ flag, void* __restrict__ out) {
  const int idx8 = blockIdx.x * 256 + threadIdx.x;
  const int r = idx8 >> 11;
  const int o = r & 255;
  float mean = st[o * 2], istd = st[o * 2 + 1];
  float g = b2f(gamma[o]), be = b2f(beta[o]);
  uint4 v = ((const uint4*)y)[idx8];
  float f[8];
  unpack8(v, f);
  float rr[8];
  #pragma unroll
  for (int k = 0; k < 8; k++) rr[k] = fmaxf((f[k] - mean) * istd * g + be, 0.f);
  if (*flag) {
    float* of = (float*)out + (size_t)idx8 * 8;
    *(float4*)of = make_float4(rr[0], rr[1], rr[2], rr[3]);
    *(float4*)(of + 4) = make_float4(rr[4], rr[5], rr[6], rr[7]);
  } else {
    u32 p0 = (u32)f2b(rr[0]) | ((u32)f2b(rr[1]) << 16);
    u32 p1 = (u32)f2b(rr[2]) | ((u32)f2b(rr[3]) << 16);
    u32 p2 = (u32)f2b(rr[4]) | ((u32)f2b(rr[5]) << 16);
    u32 p3 = (u32)f2b(rr[6]) | ((u32)f2b(rr[7]) << 16);
    ((uint4*)out)[idx8] = make_uint4(p0, p1, p2, p3);
  }
}

// ----------------------------------------------------------------------------
extern "C" void kernel_launch(void* const* d_in, const int* in_sizes, int n_in,
                              void* d_out, int out_size, void* d_ws, size_t ws_size,
                              hipStream_t stream) {
  float* G     = (float*)d_ws;           // 819,200 f32 (2 x G_SZ)
  float* score = G + 819200;             // 262,144
  float* invQ  = score + 262144;         // 512
  float* invK  = invQ + 512;             // 4,096
  float* W2    = invK + 4096;            // 524,288
  float* Wfin  = W2 + 524288;            // slot reused: u16 Wfin16
  float* bnst  = Wfin + 524288;          // 512
  int* flag    = (int*)(bnst + 512);     // 16
  u16* Sbuf    = (u16*)(flag + 16);      // S_TOTAL u16
  u16* Mbuf    = Sbuf + S_TOTAL;         // 37,748,736 u16
  u16* ybuf    = Mbuf + 37748736;        // 8,388,608 u16
  u16* Wfin16  = (u16*)Wfin;
  float* lgbuf = (float*)ybuf;           // alias: consumed before y_gemm writes ybuf

  probe<<<1, 64, 0, stream>>>((const u32*)d_in[10], flag);
  convert_all<<<dim3(1024, 1, 12), 256, 0, stream>>>(
      d_in[0], d_in[1], d_in[2], d_in[3], d_in[4], d_in[5], d_in[6], d_in[7],
      d_in[8], d_in[9], d_in[10], d_in[11], Sbuf, flag);

  sur_w<<<dim3(128, 2, 4), 256, 0, stream>>>(
      Sbuf + S_CEN, Sbuf + S_W1, Sbuf + S_B1, Sbuf + S_W2, Sbuf + S_B2,
      Sbuf + S_SW, lgbuf);
  sur_scatter<<<dim3(32, 4, 8), 256, 0, stream>>>(
      Sbuf + S_CEN, lgbuf, Sbuf + S_SW, Mbuf);
  hipMemsetAsync(G, 0, 819200 * sizeof(float), stream);
  gram_mfma<<<672, 256, 0, stream>>>(Mbuf, G);
  mirror_S<<<8, 256, 0, stream>>>(G);
  qnorm<<<8, 64, 0, stream>>>(Sbuf + S_QW, G, invQ);
  knorm<<<dim3(512, 4, 2), 256, 0, stream>>>(Sbuf + S_KW, G, invK);
  score2<<<dim3(8, 4, 2), 256, 0, stream>>>(Sbuf + S_QW, Sbuf + S_KW, G, score);
  in_softmax<<<8, 256, 0, stream>>>(score, invQ, invK);
  attnW2<<<dim3(16, 8, 2), 256, 0, stream>>>(score, Sbuf + S_VW, W2);
  wfin_k<<<dim3(1024, 2), 256, 0, stream>>>(Sbuf + S_OW, W2, Wfin16);
  y_gemm_mfma<<<dim3(128, 2, 2), 256, 0, stream>>>(Wfin16, Mbuf, ybuf);
  bn_stats<<<256, 256, 0, stream>>>(ybuf, bnst);
  bn_apply<<<4096, 256, 0, stream>>>(ybuf, bnst, Sbuf + S_GAMMA, Sbuf + S_BETA,
                                     flag, d_out);
}